// Round 12
// baseline (175.000 us; speedup 1.0000x reference)
//
#include <hip/hip_runtime.h>
#include <stdint.h>

#define NB 8
#define ND 2048
#define NH 256

typedef __attribute__((ext_vector_type(8))) short bf16x8;
typedef __attribute__((ext_vector_type(4))) float f32x4;
typedef __attribute__((ext_vector_type(16))) float f32x16;
typedef __attribute__((ext_vector_type(4))) int   i32x4;
typedef __attribute__((ext_vector_type(2))) unsigned int u32x2;
typedef __attribute__((ext_vector_type(4))) unsigned int u32x4;

#define MFMA16 __builtin_amdgcn_mfma_f32_16x16x32_bf16
#define MFMA32 __builtin_amdgcn_mfma_f32_32x32x16_bf16

__device__ __forceinline__ unsigned short f2bf(float f) {
    union { float f; unsigned int u; } c; c.f = f;
    unsigned int u = c.u + 0x7FFFu + ((c.u >> 16) & 1u);
    return (unsigned short)(u >> 16);
}
__device__ __forceinline__ unsigned int pack2(float a, float b) {
    return (unsigned int)f2bf(a) | ((unsigned int)f2bf(b) << 16);
}
__device__ __forceinline__ unsigned int cvtpk(float a, float b) {
    unsigned int r;
    asm("v_cvt_pk_bf16_f32 %0, %1, %2" : "=v"(r) : "v"(a), "v"(b));
    return r;
}
__device__ __forceinline__ void plswap(unsigned int& a, unsigned int& b) {
    asm volatile("v_permlane32_swap_b32 %0, %1" : "+v"(a), "+v"(b));
}
__device__ __forceinline__ bf16x8 mk8(unsigned int a, unsigned int b, unsigned int c, unsigned int d) {
    union { unsigned int u[4]; bf16x8 v; } x;
    x.u[0] = a; x.u[1] = b; x.u[2] = c; x.u[3] = d;
    return x.v;
}
__device__ __forceinline__ void gload_lds16(const void* g, void* l) {
    __builtin_amdgcn_global_load_lds(
        (const __attribute__((address_space(1))) void*)g,
        (__attribute__((address_space(3))) void*)l, 16, 0, 0);
}
__device__ __forceinline__ float bflo(unsigned int u) { return __uint_as_float(u << 16); }
__device__ __forceinline__ float bfhi(unsigned int u) { return __uint_as_float(u & 0xffff0000u); }

// ---------------------------------------------------------------------------
// Kernel 1 (combined): qkv projections + adj->bitmask pack (mask32 layout).
//   q row-major; kb[b][koct 32][e 2048][8]; vT[b][eoct 256][o 256][8]
//   mask32[(b*64 + tile)*2048 + row_local] u32: bit j = adj[row][tile*32+j] > 0
// ---------------------------------------------------------------------------
__global__ __launch_bounds__(256) void prep_kernel(
    const float* __restrict__ x,
    const float* __restrict__ Wq, const float* __restrict__ Wk, const float* __restrict__ Wv,
    const int* __restrict__ adj,
    unsigned short* __restrict__ qb, unsigned short* __restrict__ kb,
    unsigned short* __restrict__ vT, unsigned int* __restrict__ mask32)
{
    __shared__ unsigned short Wt[64][264];
    __shared__ unsigned short Xt[64][264];

    const int bid = blockIdx.x;          // 1536 blocks: bid%3<2 -> qkv, ==2 -> pack
    const int r3 = bid % 3, q3 = bid / 3;
    const int t = threadIdx.x;

    if (r3 == 2) {
        // ---- pack: 512 blocks, 4 waves, 8 rows/wave, 16 loads in flight ----
        const int w = t >> 6, l = t & 63;
        const int wave_id = q3 * 4 + w;          // 0..2047
#pragma unroll 1
        for (int k = 0; k < 8; ++k) {
            const int rg = wave_id + k * 2048;   // global row 0..16383
            const int bb = rg >> 11, rl = rg & 2047;
            const int* ar = adj + (size_t)rg * ND;
            unsigned int* mb_ = mask32 + ((size_t)bb * 64) * 2048 + rl;
#pragma unroll 1
            for (int ib = 0; ib < 2; ++ib) {
                int v[16];
#pragma unroll
                for (int i2 = 0; i2 < 16; ++i2)
                    v[i2] = ar[(ib * 16 + i2) * 64 + l];
#pragma unroll
                for (int i2 = 0; i2 < 16; ++i2) {
                    unsigned long long bl = __ballot(v[i2] > 0);
                    if (l == 0) {
                        const int tile = (ib * 16 + i2) * 2;
                        mb_[(size_t)tile * 2048]       = (unsigned int)bl;
                        mb_[(size_t)(tile + 1) * 2048] = (unsigned int)(bl >> 32);
                    }
                }
            }
        }
        return;
    }

    // ---- qkv: 1024 blocks ----
    const int qidx = q3 * 2 + r3;
    const int m0 = (qidx & 255) * 64;
    const int o0 = (qidx >> 8) * 64;
    const int w = t >> 6, lane = t & 63, lr = lane & 15, half = lane >> 4;
    const int ar0 = 32 * (w >> 1), br0 = 32 * (w & 1);

#pragma unroll
    for (int i = 0; i < 16; ++i) {
        int fidx = i * 256 + t, row = fidx >> 6, c4 = fidx & 63;
        f32x4 vW = *reinterpret_cast<const f32x4*>(Wq + (size_t)(o0 + row) * NH + c4 * 4);
        f32x4 vX = *reinterpret_cast<const f32x4*>(x + (size_t)(m0 + row) * NH + c4 * 4);
        u32x2 pw; pw[0] = pack2(vW[0], vW[1]); pw[1] = pack2(vW[2], vW[3]);
        u32x2 px; px[0] = pack2(vX[0], vX[1]); px[1] = pack2(vX[2], vX[3]);
        *reinterpret_cast<u32x2*>(&Wt[row][c4 * 4]) = pw;
        *reinterpret_cast<u32x2*>(&Xt[row][c4 * 4]) = px;
    }
    __syncthreads();

    for (int z = 0; z < 3; ++z) {
        const unsigned short (*Ab)[264] = (z == 2) ? Xt : Wt;
        const unsigned short (*Bb)[264] = (z == 2) ? Wt : Xt;

        f32x4 acc[2][2] = {};
#pragma unroll
        for (int kk = 0; kk < 8; ++kk) {
            bf16x8 a[2], bfr[2];
#pragma unroll
            for (int f = 0; f < 2; ++f) {
                a[f]   = *reinterpret_cast<const bf16x8*>(&Ab[ar0 + 16 * f + lr][32 * kk + 8 * half]);
                bfr[f] = *reinterpret_cast<const bf16x8*>(&Bb[br0 + 16 * f + lr][32 * kk + 8 * half]);
            }
#pragma unroll
            for (int fa = 0; fa < 2; ++fa)
#pragma unroll
                for (int fb = 0; fb < 2; ++fb)
                    acc[fa][fb] = MFMA16(a[fa], bfr[fb], acc[fa][fb], 0, 0, 0);
        }

        if (z == 0) {
#pragma unroll
            for (int fa = 0; fa < 2; ++fa)
#pragma unroll
                for (int fb = 0; fb < 2; ++fb) {
                    int m = m0 + br0 + 16 * fb + lr;
                    int o = o0 + ar0 + 16 * fa + 4 * half;
                    u32x2 pk; pk[0] = pack2(acc[fa][fb][0], acc[fa][fb][1]);
                    pk[1] = pack2(acc[fa][fb][2], acc[fa][fb][3]);
                    *reinterpret_cast<u32x2*>(qb + (size_t)m * NH + o) = pk;
                }
        } else if (z == 1) {
#pragma unroll
            for (int fa = 0; fa < 2; ++fa)
#pragma unroll
                for (int fb = 0; fb < 2; ++fb) {
                    int m = m0 + br0 + 16 * fb + lr;          // token e
                    int o = o0 + ar0 + 16 * fa + 4 * half;    // k-feature
                    int bb = m >> 11, el = m & 2047;
                    u32x2 pk; pk[0] = pack2(acc[fa][fb][0], acc[fa][fb][1]);
                    pk[1] = pack2(acc[fa][fb][2], acc[fa][fb][3]);
                    size_t idx = (((size_t)bb * 32 + (o >> 3)) * 2048 + el) * 8 + (o & 7);
                    *reinterpret_cast<u32x2*>(kb + idx) = pk;
                }
        } else {
#pragma unroll
            for (int fa = 0; fa < 2; ++fa)
#pragma unroll
                for (int fb = 0; fb < 2; ++fb) {
                    int dg = m0 + ar0 + 16 * fa + 4 * half;   // token e
                    int o  = o0 + br0 + 16 * fb + lr;         // out feature
                    int bb = dg >> 11, el = dg & 2047;
                    u32x2 pk; pk[0] = pack2(acc[fa][fb][0], acc[fa][fb][1]);
                    pk[1] = pack2(acc[fa][fb][2], acc[fa][fb][3]);
                    size_t idx = (((size_t)bb * 256 + (el >> 3)) * 256 + o) * 8 + (el & 7);
                    *reinterpret_cast<u32x2*>(vT + idx) = pk;
                }
        }

        if (z < 2) {
            __syncthreads();
            const float* Wn = (z == 0) ? Wk : Wv;
#pragma unroll
            for (int i = 0; i < 16; ++i) {
                int fidx = i * 256 + t, row = fidx >> 6, c4 = fidx & 63;
                f32x4 vW = *reinterpret_cast<const f32x4*>(Wn + (size_t)(o0 + row) * NH + c4 * 4);
                u32x2 pw; pw[0] = pack2(vW[0], vW[1]); pw[1] = pack2(vW[2], vW[3]);
                *reinterpret_cast<u32x2*>(&Wt[row][c4 * 4]) = pw;
            }
            __syncthreads();
        }
    }
}

// ---------------------------------------------------------------------------
// Kernel 2: flash attention partials, software-pipelined:
// triple-buffered K/V (96KB LDS); per tile: stage(t+2) || QK(t+1) [MFMA]
// || softmax(t) [VALU issues under QK's execution] || PV(t). One barrier/tile.
// 8 waves; pair shares 32 q-rows (QK dup), PV split by o-half (acc[4]).
// mask32: one coalesced u32 load per tile per lane.
// ---------------------------------------------------------------------------
template<int ESP>
__global__ __launch_bounds__(512, 2) void attn_kernel(
    const unsigned short* __restrict__ qb, const unsigned short* __restrict__ kb,
    const unsigned short* __restrict__ vT, const unsigned int* __restrict__ mask32,
    unsigned short* __restrict__ part, float* __restrict__ mpart, float* __restrict__ lpart)
{
    constexpr int QB = 128;                  // q-rows per block
    constexpr int NOT = 4;                   // 32-o tiles per wave (o-half)
    constexpr int NT = (ND / ESP) / 32;      // 32-e tiles per block

    __shared__ unsigned char KT[3][16384];   // [koct 32][e 32][16B]
    __shared__ unsigned char VTl[3][16384];  // [eoct 4][o 256][16B]

    const int bid = blockIdx.x;
    const int b = bid & 7, es0 = (bid >> 3) & (ESP - 1), qt = bid / (8 * ESP);
    const int t = threadIdx.x, w = t >> 6, l = t & 63;
    const int lo32 = l & 31, hi = l >> 5;
    const int g = w & 3, side = w >> 2;
    const int qbase = qt * QB + g * 32;
    const int obase = side * 128;
    const int ebase = es0 * (ND / ESP);
    const float SC = 0.0625f, L2E = 1.44269504f;

    bf16x8 qf[16];
    {
        const unsigned short* qr = qb + ((size_t)b * ND + qbase + lo32) * NH + 8 * hi;
#pragma unroll
        for (int kk = 0; kk < 16; ++kk)
            qf[kk] = *reinterpret_cast<const bf16x8*>(qr + kk * 16);
    }

    const char* kbc = (const char*)kb + ((size_t)b << 20);
    const char* vtc = (const char*)vT + ((size_t)b << 20);
    const unsigned int* mrow =
        mask32 + ((size_t)b * 64 + es0 * NT) * 2048 + qbase + lo32;

    auto stageK = [&](int buf, int tt) {
        const int e0s = ebase + tt * 32;
#pragma unroll
        for (int i = 0; i < 2; ++i) {
            int off = i * 8192 + t * 16;
            int koct = off >> 9, e = (off >> 4) & 31;
            gload_lds16(kbc + (size_t)koct * 32768 + (size_t)(e0s + e) * 16, &KT[buf][off]);
        }
    };
    auto stageV = [&](int buf, int tt) {
        const int Eb = (ebase + tt * 32) >> 3;
#pragma unroll
        for (int i = 0; i < 2; ++i) {
            int off = i * 8192 + t * 16;
            int eoct = off >> 12, o = (off >> 4) & 255;
            gload_lds16(vtc + (size_t)(Eb + eoct) * 4096 + (size_t)o * 16, &VTl[buf][off]);
        }
    };

    f32x16 acc[NOT] = {};
    float m_run = -__builtin_inff(), l_run = 0.f;

    // ---- prologue: buf0 staged+ready; buf1 in flight; QK(0) computed ----
    stageK(0, 0); stageV(0, 0);
    __syncthreads();
    if (NT > 1) { stageK(1, 1); stageV(1, 1); }
    f32x16 scn0 = {}, scn1 = {};
    {
        const char* Kc = (const char*)&KT[0][0];
#pragma unroll
        for (int kk = 0; kk < 16; kk += 2) {
            bf16x8 kf0 = *reinterpret_cast<const bf16x8*>(Kc + kk * 1024 + hi * 512 + lo32 * 16);
            bf16x8 kf1 = *reinterpret_cast<const bf16x8*>(Kc + (kk + 1) * 1024 + hi * 512 + lo32 * 16);
            scn0 = MFMA32(kf0, qf[kk], scn0, 0, 0, 0);
            scn1 = MFMA32(kf1, qf[kk + 1], scn1, 0, 0, 0);
        }
    }
    unsigned int m_cur = mrow[0];
    __syncthreads();   // buf1 ready

    int ib_pv = 0, ib_qk = 1, ib_st = 2;

#pragma unroll 1
    for (int tt = 0; tt < NT; ++tt) {
        // ---- collapse previous QK pair into current scores ----
        f32x16 scc;
#pragma unroll
        for (int r = 0; r < 16; ++r) scc[r] = scn0[r] + scn1[r];

        // ---- stage(t+2) ----
        if (tt + 2 < NT) { stageK(ib_st, tt + 2); stageV(ib_st, tt + 2); }
        const unsigned int m_next = (tt + 1 < NT) ? mrow[(size_t)(tt + 1) * 2048] : 0u;

        // ---- QK(t+1): MFMA, independent of softmax(t) below ----
        scn0 = (f32x16){}; scn1 = (f32x16){};
        if (tt + 1 < NT) {
            const char* Kc = (const char*)&KT[ib_qk][0];
#pragma unroll
            for (int kk = 0; kk < 16; kk += 2) {
                bf16x8 kf0 = *reinterpret_cast<const bf16x8*>(Kc + kk * 1024 + hi * 512 + lo32 * 16);
                bf16x8 kf1 = *reinterpret_cast<const bf16x8*>(Kc + (kk + 1) * 1024 + hi * 512 + lo32 * 16);
                scn0 = MFMA32(kf0, qf[kk], scn0, 0, 0, 0);
                scn1 = MFMA32(kf1, qf[kk + 1], scn1, 0, 0, 0);
            }
        }

        // ---- mask + online softmax (defer-max) for tile t ----
        float p[16];
        float tmax = -__builtin_inff();
        const unsigned int mb = m_cur >> (4 * hi);
#pragma unroll
        for (int gg = 0; gg < 4; ++gg) {
            const unsigned int mg = mb >> (8 * gg);
#pragma unroll
            for (int r = 0; r < 4; ++r) {
                float sv = scc[gg * 4 + r] * SC;
                sv = ((mg >> r) & 1u) ? sv : -1e9f;
                p[gg * 4 + r] = sv;
                tmax = fmaxf(tmax, sv);
            }
        }
        tmax = fmaxf(tmax, __shfl_xor(tmax, 32));
        if (!__all(tmax <= m_run + 8.0f)) {
            const float m_new = fmaxf(m_run, tmax);
            const float scale = exp2f((m_run - m_new) * L2E);
#pragma unroll
            for (int ot = 0; ot < NOT; ++ot)
#pragma unroll
                for (int r = 0; r < 16; ++r) acc[ot][r] *= scale;
            l_run *= scale;
            m_run = m_new;
        }
        float psum = 0.f;
#pragma unroll
        for (int r2 = 0; r2 < 16; ++r2) {
            float pe = exp2f((p[r2] - m_run) * L2E);
            p[r2] = pe;
            psum += pe;
        }
        psum += __shfl_xor(psum, 32);
        l_run += psum;

        // ---- P -> B-frags in-register ----
        unsigned int c0 = cvtpk(p[0], p[1]),   c1 = cvtpk(p[2], p[3]);
        unsigned int c2 = cvtpk(p[4], p[5]),   c3 = cvtpk(p[6], p[7]);
        plswap(c0, c2); plswap(c1, c3);
        unsigned int c4 = cvtpk(p[8], p[9]),   c5 = cvtpk(p[10], p[11]);
        unsigned int c6 = cvtpk(p[12], p[13]), c7 = cvtpk(p[14], p[15]);
        plswap(c4, c6); plswap(c5, c7);
        const bf16x8 pf0 = mk8(c0, c1, c2, c3);
        const bf16x8 pf1 = mk8(c4, c5, c6, c7);

        // ---- PV(t): this wave's o-half ----
        const char* Vc = (const char*)&VTl[ib_pv][0];
#pragma unroll
        for (int ot = 0; ot < NOT; ++ot) {
            bf16x8 vf = *reinterpret_cast<const bf16x8*>(
                Vc + hi * 4096 + (size_t)(obase + ot * 32 + lo32) * 16);
            acc[ot] = MFMA32(vf, pf0, acc[ot], 0, 0, 0);
        }
#pragma unroll
        for (int ot = 0; ot < NOT; ++ot) {
            bf16x8 vf = *reinterpret_cast<const bf16x8*>(
                Vc + 8192 + hi * 4096 + (size_t)(obase + ot * 32 + lo32) * 16);
            acc[ot] = MFMA32(vf, pf1, acc[ot], 0, 0, 0);
        }

        __syncthreads();   // drains stage(t+2); buffers rotate safely
        m_cur = m_next;
        const int tmp = ib_pv; ib_pv = ib_qk; ib_qk = ib_st; ib_st = tmp;
    }

    // ---- epilogue: unnormalized bf16 partials + m/l ----
    const int qg = b * ND + qbase + lo32;
    unsigned short* pb = part + ((size_t)es0 * 16384 + qg) * 256;
#pragma unroll
    for (int ot = 0; ot < NOT; ++ot)
#pragma unroll
        for (int g2 = 0; g2 < 4; ++g2) {
            u32x2 pk;
            pk[0] = pack2(acc[ot][g2 * 4 + 0], acc[ot][g2 * 4 + 1]);
            pk[1] = pack2(acc[ot][g2 * 4 + 2], acc[ot][g2 * 4 + 3]);
            *reinterpret_cast<u32x2*>(pb + obase + ot * 32 + g2 * 8 + 4 * hi) = pk;
        }
    if (hi == 0 && side == 0) {
        mpart[(size_t)es0 * 16384 + qg] = m_run;
        lpart[(size_t)es0 * 16384 + qg] = l_run;
    }
}

// ---------------------------------------------------------------------------
// Kernel 3: fused combine + out-projection + residual + LayerNorm.
// ---------------------------------------------------------------------------
template<int ESP>
__global__ __launch_bounds__(256) void fuse_kernel(
    const unsigned short* __restrict__ part, const float* __restrict__ mpart,
    const float* __restrict__ lpart, const float* __restrict__ Wp,
    const float* __restrict__ bp, const float* __restrict__ x,
    const float* __restrict__ gamma, const float* __restrict__ beta,
    float* __restrict__ out)
{
    __shared__ unsigned short Xt[64][264];
    __shared__ unsigned short Wt[64][264];
    __shared__ float hL[64][264];
    __shared__ float cel[64][ESP];

    const int M0 = blockIdx.x * 64;
    const int t = threadIdx.x;
    const float L2E = 1.44269504f;

    if (t < 64) {
        float me[ESP], le[ESP], M = -__builtin_inff();
#pragma unroll
        for (int e = 0; e < ESP; ++e) {
            me[e] = mpart[(size_t)e * 16384 + M0 + t];
            le[e] = lpart[(size_t)e * 16384 + M0 + t];
            M = fmaxf(M, me[e]);
        }
        float wsum = 0.f;
#pragma unroll
        for (int e = 0; e < ESP; ++e) { me[e] = exp2f((me[e] - M) * L2E); wsum += me[e] * le[e]; }
        const float inv = 1.f / wsum;
#pragma unroll
        for (int e = 0; e < ESP; ++e) cel[t][e] = me[e] * inv;
    }
#pragma unroll
    for (int i = 0; i < 16; ++i) {
        int fidx = i * 256 + t, row = fidx >> 6, c4 = fidx & 63;
        f32x4 vW = *reinterpret_cast<const f32x4*>(Wp + (size_t)row * NH + c4 * 4);
        u32x2 pw; pw[0] = pack2(vW[0], vW[1]); pw[1] = pack2(vW[2], vW[3]);
        *reinterpret_cast<u32x2*>(&Wt[row][c4 * 4]) = pw;
    }
    __syncthreads();

#pragma unroll
    for (int i = 0; i < 8; ++i) {
        int fidx = i * 256 + t, row = fidx >> 5, c8 = fidx & 31;
        float o[8] = {};
#pragma unroll
        for (int e = 0; e < ESP; ++e) {
            u32x4 v = *reinterpret_cast<const u32x4*>(
                part + (((size_t)e * 16384 + M0 + row) * 256 + c8 * 8));
            const float ce = cel[row][e];
#pragma unroll
            for (int j = 0; j < 4; ++j) {
                o[2 * j]     += ce * bflo(v[j]);
                o[2 * j + 1] += ce * bfhi(v[j]);
            }
        }
        u32x4 pk;
#pragma unroll
        for (int j = 0; j < 4; ++j) pk[j] = pack2(o[2 * j], o[2 * j + 1]);
        *reinterpret_cast<u32x4*>(&Xt[row][c8 * 8]) = pk;
    }
    __syncthreads();

    const int w = t >> 6, lane = t & 63, lr = lane & 15, half = lane >> 4;
    const int ar0 = 32 * (w >> 1), br0 = 32 * (w & 1);

    for (int pc = 0; pc < 4; ++pc) {
        f32x4 acc[2][2] = {};
#pragma unroll
        for (int kk = 0; kk < 8; ++kk) {
            bf16x8 a[2], bfr[2];
#pragma unroll
            for (int f = 0; f < 2; ++f) {
                a[f]   = *reinterpret_cast<const bf16x8*>(&Wt[ar0 + 16 * f + lr][32 * kk + 8 * half]);
                bfr[f] = *reinterpret_cast<const bf16x8*>(&Xt[br0 + 16 * f + lr][32 * kk + 8 * half]);
            }
#pragma unroll
            for (int fa = 0; fa < 2; ++fa)
#pragma unroll
                for (int fb = 0; fb < 2; ++fb)
                    acc[fa][fb] = MFMA16(a[fa], bfr[fb], acc[fa][fb], 0, 0, 0);
        }
#pragma unroll
        for (int fa = 0; fa < 2; ++fa)
#pragma unroll
            for (int fb = 0; fb < 2; ++fb) {
                int p = pc * 64 + ar0 + 16 * fa + 4 * half;
                int m = br0 + 16 * fb + lr;
                *reinterpret_cast<f32x4*>(&hL[m][p]) = acc[fa][fb];
            }
        if (pc < 3) {
            __syncthreads();
#pragma unroll
            for (int i = 0; i < 16; ++i) {
                int fidx = i * 256 + t, row = fidx >> 6, c4 = fidx & 63;
                f32x4 vW = *reinterpret_cast<const f32x4*>(
                    Wp + (size_t)((pc + 1) * 64 + row) * NH + c4 * 4);
                u32x2 pw; pw[0] = pack2(vW[0], vW[1]); pw[1] = pack2(vW[2], vW[3]);
                *reinterpret_cast<u32x2*>(&Wt[row][c4 * 4]) = pw;
            }
            __syncthreads();
        }
    }
    __syncthreads();

    f32x4 gm = *reinterpret_cast<const f32x4*>(gamma + lane * 4);
    f32x4 be = *reinterpret_cast<const f32x4*>(beta + lane * 4);
    f32x4 bv = *reinterpret_cast<const f32x4*>(bp + lane * 4);
    for (int rr = 0; rr < 16; ++rr) {
        const int row = w * 16 + rr;
        f32x4 v = *reinterpret_cast<const f32x4*>(&hL[row][lane * 4]);
        f32x4 xr = *reinterpret_cast<const f32x4*>(x + (size_t)(M0 + row) * NH + lane * 4);
#pragma unroll
        for (int r = 0; r < 4; ++r) v[r] += xr[r] + bv[r];
        float s = v[0] + v[1] + v[2] + v[3];
#pragma unroll
        for (int off = 1; off < 64; off <<= 1) s += __shfl_xor(s, off);
        const float mu = s * (1.f / 256.f);
        f32x4 dv; float q = 0.f;
#pragma unroll
        for (int r = 0; r < 4; ++r) { dv[r] = v[r] - mu; q += dv[r] * dv[r]; }
#pragma unroll
        for (int off = 1; off < 64; off <<= 1) q += __shfl_xor(q, off);
        const float rs = rsqrtf(q * (1.f / 256.f) + 1e-5f);
        f32x4 o;
#pragma unroll
        for (int r = 0; r < 4; ++r) o[r] = dv[r] * rs * gm[r] + be[r];
        *reinterpret_cast<f32x4*>(out + (size_t)(M0 + row) * NH + lane * 4) = o;
    }
}

extern "C" void kernel_launch(void* const* d_in, const int* in_sizes, int n_in,
                              void* d_out, int out_size, void* d_ws, size_t ws_size,
                              hipStream_t stream)
{
    const float* x     = (const float*)d_in[0];
    const int*   adj   = (const int*)d_in[1];
    const float* Wq    = (const float*)d_in[2];
    const float* Wk    = (const float*)d_in[3];
    const float* Wv    = (const float*)d_in[4];
    const float* Wp    = (const float*)d_in[5];
    const float* bp    = (const float*)d_in[6];
    const float* gamma = (const float*)d_in[7];
    const float* beta  = (const float*)d_in[8];

    char* ws = (char*)d_ws;
    const size_t MB = 1024 * 1024;
    unsigned short* qb    = (unsigned short*)(ws);
    unsigned short* kb    = (unsigned short*)(ws + 8 * MB);
    unsigned short* vT    = (unsigned short*)(ws + 16 * MB);
    unsigned short* partb = (unsigned short*)(ws + 24 * MB);
    float* out = (float*)d_out;

    const bool big = ws_size >= (size_t)62 * MB;
    if (big) {
        float* mpart = (float*)(ws + 56 * MB);
        float* lpart = (float*)(ws + 56 * MB + 256 * 1024);
        unsigned int* mask32 = (unsigned int*)(ws + 57 * MB);
        prep_kernel<<<dim3(1536), 256, 0, stream>>>(x, Wq, Wk, Wv, adj, qb, kb, vT, mask32);
        attn_kernel<4><<<dim3(512), 512, 0, stream>>>(qb, kb, vT, mask32, partb, mpart, lpart);
        fuse_kernel<4><<<dim3(256), 256, 0, stream>>>(partb, mpart, lpart, Wp, bp, x, gamma, beta, out);
    } else {
        float* mpart = (float*)(ws + 40 * MB);
        float* lpart = (float*)(ws + 40 * MB + 128 * 1024);
        unsigned int* mask32 = (unsigned int*)(ws + 41 * MB);
        prep_kernel<<<dim3(1536), 256, 0, stream>>>(x, Wq, Wk, Wv, adj, qb, kb, vT, mask32);
        attn_kernel<2><<<dim3(256), 512, 0, stream>>>(qb, kb, vT, mask32, partb, mpart, lpart);
        fuse_kernel<2><<<dim3(256), 256, 0, stream>>>(partb, mpart, lpart, Wp, bp, x, gamma, beta, out);
    }
}

// Round 13
// 165.715 us; speedup vs baseline: 1.0560x; 1.0560x over previous
//
#include <hip/hip_runtime.h>
#include <stdint.h>

#define NB 8
#define ND 2048
#define NH 256

typedef __attribute__((ext_vector_type(8))) short bf16x8;
typedef __attribute__((ext_vector_type(4))) float f32x4;
typedef __attribute__((ext_vector_type(16))) float f32x16;
typedef __attribute__((ext_vector_type(4))) int   i32x4;
typedef __attribute__((ext_vector_type(2))) unsigned int u32x2;
typedef __attribute__((ext_vector_type(4))) unsigned int u32x4;

#define MFMA16 __builtin_amdgcn_mfma_f32_16x16x32_bf16
#define MFMA32 __builtin_amdgcn_mfma_f32_32x32x16_bf16

__device__ __forceinline__ unsigned short f2bf(float f) {
    union { float f; unsigned int u; } c; c.f = f;
    unsigned int u = c.u + 0x7FFFu + ((c.u >> 16) & 1u);
    return (unsigned short)(u >> 16);
}
__device__ __forceinline__ unsigned int pack2(float a, float b) {
    return (unsigned int)f2bf(a) | ((unsigned int)f2bf(b) << 16);
}
__device__ __forceinline__ unsigned int cvtpk(float a, float b) {
    unsigned int r;
    asm("v_cvt_pk_bf16_f32 %0, %1, %2" : "=v"(r) : "v"(a), "v"(b));
    return r;
}
__device__ __forceinline__ void plswap(unsigned int& a, unsigned int& b) {
    asm volatile("v_permlane32_swap_b32 %0, %1" : "+v"(a), "+v"(b));
}
__device__ __forceinline__ bf16x8 mk8(unsigned int a, unsigned int b, unsigned int c, unsigned int d) {
    union { unsigned int u[4]; bf16x8 v; } x;
    x.u[0] = a; x.u[1] = b; x.u[2] = c; x.u[3] = d;
    return x.v;
}
__device__ __forceinline__ void gload_lds16(const void* g, void* l) {
    __builtin_amdgcn_global_load_lds(
        (const __attribute__((address_space(1))) void*)g,
        (__attribute__((address_space(3))) void*)l, 16, 0, 0);
}
__device__ __forceinline__ float bflo(unsigned int u) { return __uint_as_float(u << 16); }
__device__ __forceinline__ float bfhi(unsigned int u) { return __uint_as_float(u & 0xffff0000u); }

// ---------------------------------------------------------------------------
// Kernel 1: qkv (x staged ONCE per m-tile, loops z x o-chunk) + adj->u64 pack.
//   grid 768: bid%3==0 -> qkv (256 blocks), else pack (512 blocks).
//   q row-major; kb[b][koct 32][e 2048][8]; vT[b][eoct 256][o 256][8]
//   maskb[row 16384][chunk 8][r 4] u64: bit l = adj[row][chunk*256+4*l+r] > 0
// ---------------------------------------------------------------------------
__global__ __launch_bounds__(256) void prep_kernel(
    const float* __restrict__ x,
    const float* __restrict__ Wq, const float* __restrict__ Wk, const float* __restrict__ Wv,
    const int* __restrict__ adj,
    unsigned short* __restrict__ qb, unsigned short* __restrict__ kb,
    unsigned short* __restrict__ vT, unsigned long long* __restrict__ maskb)
{
    __shared__ unsigned short Wt[64][264];
    __shared__ unsigned short Xt[64][264];

    const int bid = blockIdx.x;
    const int r3 = bid % 3, q3 = bid / 3;
    const int t = threadIdx.x;

    if (r3 != 0) {
        // ---- pack: 512 blocks, 4 waves, 8 rows/wave, 16 x 16B loads in flight ----
        const int pi = q3 * 2 + (r3 - 1);        // 0..511
        const int w = t >> 6, l = t & 63;
        const int wave_id = pi * 4 + w;          // 0..2047
#pragma unroll 1
        for (int k = 0; k < 8; k += 2) {
            const int row0 = wave_id + k * 2048;
            const int row1 = wave_id + (k + 1) * 2048;
            const int* ar0_ = adj + (size_t)row0 * ND;
            const int* ar1_ = adj + (size_t)row1 * ND;
            i32x4 v0[8], v1[8];
#pragma unroll
            for (int cc = 0; cc < 8; ++cc)
                v0[cc] = *reinterpret_cast<const i32x4*>(ar0_ + cc * 256 + l * 4);
#pragma unroll
            for (int cc = 0; cc < 8; ++cc)
                v1[cc] = *reinterpret_cast<const i32x4*>(ar1_ + cc * 256 + l * 4);
#pragma unroll
            for (int cc = 0; cc < 8; ++cc) {
                unsigned long long b0 = __ballot(v0[cc][0] > 0);
                unsigned long long b1 = __ballot(v0[cc][1] > 0);
                unsigned long long b2 = __ballot(v0[cc][2] > 0);
                unsigned long long b3 = __ballot(v0[cc][3] > 0);
                if (l == 0) {
                    unsigned long long* dst = maskb + ((size_t)row0 * 8 + cc) * 4;
                    dst[0] = b0; dst[1] = b1; dst[2] = b2; dst[3] = b3;
                }
            }
#pragma unroll
            for (int cc = 0; cc < 8; ++cc) {
                unsigned long long b0 = __ballot(v1[cc][0] > 0);
                unsigned long long b1 = __ballot(v1[cc][1] > 0);
                unsigned long long b2 = __ballot(v1[cc][2] > 0);
                unsigned long long b3 = __ballot(v1[cc][3] > 0);
                if (l == 0) {
                    unsigned long long* dst = maskb + ((size_t)row1 * 8 + cc) * 4;
                    dst[0] = b0; dst[1] = b1; dst[2] = b2; dst[3] = b3;
                }
            }
        }
        return;
    }

    // ---- qkv: 256 blocks; x staged once; 12 GEMM tiles (3 z x 4 o-chunks) ----
    const int m0 = q3 * 64;
    const int w = t >> 6, lane = t & 63, lr = lane & 15, half = lane >> 4;
    const int ar0 = 32 * (w >> 1), br0 = 32 * (w & 1);

#pragma unroll
    for (int i = 0; i < 16; ++i) {
        int fidx = i * 256 + t, row = fidx >> 6, c4 = fidx & 63;
        f32x4 vX = *reinterpret_cast<const f32x4*>(x + (size_t)(m0 + row) * NH + c4 * 4);
        u32x2 px; px[0] = pack2(vX[0], vX[1]); px[1] = pack2(vX[2], vX[3]);
        *reinterpret_cast<u32x2*>(&Xt[row][c4 * 4]) = px;
    }

    for (int z = 0; z < 3; ++z) {
        const float* W = (z == 0) ? Wq : (z == 1 ? Wk : Wv);
        for (int oc = 0; oc < 4; ++oc) {
            const int o0 = oc * 64;
            __syncthreads();   // prior GEMM's Wt reads done (covers x-stage too)
#pragma unroll
            for (int i = 0; i < 16; ++i) {
                int fidx = i * 256 + t, row = fidx >> 6, c4 = fidx & 63;
                f32x4 vW = *reinterpret_cast<const f32x4*>(W + (size_t)(o0 + row) * NH + c4 * 4);
                u32x2 pw; pw[0] = pack2(vW[0], vW[1]); pw[1] = pack2(vW[2], vW[3]);
                *reinterpret_cast<u32x2*>(&Wt[row][c4 * 4]) = pw;
            }
            __syncthreads();

            const unsigned short (*Ab)[264] = (z == 2) ? Xt : Wt;
            const unsigned short (*Bb)[264] = (z == 2) ? Wt : Xt;

            f32x4 acc[2][2] = {};
#pragma unroll
            for (int kk = 0; kk < 8; ++kk) {
                bf16x8 a[2], bfr[2];
#pragma unroll
                for (int f = 0; f < 2; ++f) {
                    a[f]   = *reinterpret_cast<const bf16x8*>(&Ab[ar0 + 16 * f + lr][32 * kk + 8 * half]);
                    bfr[f] = *reinterpret_cast<const bf16x8*>(&Bb[br0 + 16 * f + lr][32 * kk + 8 * half]);
                }
#pragma unroll
                for (int fa = 0; fa < 2; ++fa)
#pragma unroll
                    for (int fb = 0; fb < 2; ++fb)
                        acc[fa][fb] = MFMA16(a[fa], bfr[fb], acc[fa][fb], 0, 0, 0);
            }

            if (z == 0) {
#pragma unroll
                for (int fa = 0; fa < 2; ++fa)
#pragma unroll
                    for (int fb = 0; fb < 2; ++fb) {
                        int m = m0 + br0 + 16 * fb + lr;
                        int o = o0 + ar0 + 16 * fa + 4 * half;
                        u32x2 pk; pk[0] = pack2(acc[fa][fb][0], acc[fa][fb][1]);
                        pk[1] = pack2(acc[fa][fb][2], acc[fa][fb][3]);
                        *reinterpret_cast<u32x2*>(qb + (size_t)m * NH + o) = pk;
                    }
            } else if (z == 1) {
#pragma unroll
                for (int fa = 0; fa < 2; ++fa)
#pragma unroll
                    for (int fb = 0; fb < 2; ++fb) {
                        int m = m0 + br0 + 16 * fb + lr;          // token e
                        int o = o0 + ar0 + 16 * fa + 4 * half;    // k-feature
                        int bb = m >> 11, el = m & 2047;
                        u32x2 pk; pk[0] = pack2(acc[fa][fb][0], acc[fa][fb][1]);
                        pk[1] = pack2(acc[fa][fb][2], acc[fa][fb][3]);
                        size_t idx = (((size_t)bb * 32 + (o >> 3)) * 2048 + el) * 8 + (o & 7);
                        *reinterpret_cast<u32x2*>(kb + idx) = pk;
                    }
            } else {
#pragma unroll
                for (int fa = 0; fa < 2; ++fa)
#pragma unroll
                    for (int fb = 0; fb < 2; ++fb) {
                        int dg = m0 + ar0 + 16 * fa + 4 * half;   // token e
                        int o  = o0 + br0 + 16 * fb + lr;         // out feature
                        int bb = dg >> 11, el = dg & 2047;
                        u32x2 pk; pk[0] = pack2(acc[fa][fb][0], acc[fa][fb][1]);
                        pk[1] = pack2(acc[fa][fb][2], acc[fa][fb][3]);
                        size_t idx = (((size_t)bb * 256 + (el >> 3)) * 256 + o) * 8 + (el & 7);
                        *reinterpret_cast<u32x2*>(vT + idx) = pk;
                    }
            }
        }
    }
}

// ---------------------------------------------------------------------------
// Kernel 2: flash attention partials, software-pipelined:
// triple-buffered K/V (96KB LDS); per tile: stage(t+2) || QK(t+1) [MFMA]
// || softmax(t) [VALU under QK] || PV(t). One barrier/tile.
// u64 bitmask: 4 words per 256-e chunk, prefetched one chunk ahead.
// 8 waves; pair shares 32 q-rows (QK dup), PV split by o-half (acc[4]).
// ---------------------------------------------------------------------------
template<int ESP>
__global__ __launch_bounds__(512, 2) void attn_kernel(
    const unsigned short* __restrict__ qb, const unsigned short* __restrict__ kb,
    const unsigned short* __restrict__ vT, const unsigned long long* __restrict__ maskb,
    unsigned short* __restrict__ part, float* __restrict__ mpart, float* __restrict__ lpart)
{
    constexpr int QB = 128;                  // q-rows per block
    constexpr int NOT = 4;                   // 32-o tiles per wave (o-half)
    constexpr int NT = (ND / ESP) / 32;      // 32-e tiles per block
    constexpr int NC = NT / 8;               // 256-e chunks per block

    __shared__ unsigned char KT[3][16384];   // [koct 32][e 32][16B]
    __shared__ unsigned char VTl[3][16384];  // [eoct 4][o 256][16B]

    const int bid = blockIdx.x;
    const int b = bid & 7, es0 = (bid >> 3) & (ESP - 1), qt = bid / (8 * ESP);
    const int t = threadIdx.x, w = t >> 6, l = t & 63;
    const int lo32 = l & 31, hi = l >> 5;
    const int g = w & 3, side = w >> 2;
    const int qbase = qt * QB + g * 32;
    const int obase = side * 128;
    const int ebase = es0 * (ND / ESP);
    const float SC = 0.0625f, L2E = 1.44269504f;

    bf16x8 qf[16];
    {
        const unsigned short* qr = qb + ((size_t)b * ND + qbase + lo32) * NH + 8 * hi;
#pragma unroll
        for (int kk = 0; kk < 16; ++kk)
            qf[kk] = *reinterpret_cast<const bf16x8*>(qr + kk * 16);
    }

    const char* kbc = (const char*)kb + ((size_t)b << 20);
    const char* vtc = (const char*)vT + ((size_t)b << 20);
    const unsigned long long* mrow =
        maskb + ((size_t)(b * ND + qbase + lo32) * 8 + (ebase >> 8)) * 4;

    auto stageK = [&](int buf, int tt) {
        const int e0s = ebase + tt * 32;
#pragma unroll
        for (int i = 0; i < 2; ++i) {
            int off = i * 8192 + t * 16;
            int koct = off >> 9, e = (off >> 4) & 31;
            gload_lds16(kbc + (size_t)koct * 32768 + (size_t)(e0s + e) * 16, &KT[buf][off]);
        }
    };
    auto stageV = [&](int buf, int tt) {
        const int Eb = (ebase + tt * 32) >> 3;
#pragma unroll
        for (int i = 0; i < 2; ++i) {
            int off = i * 8192 + t * 16;
            int eoct = off >> 12, o = (off >> 4) & 255;
            gload_lds16(vtc + (size_t)(Eb + eoct) * 4096 + (size_t)o * 16, &VTl[buf][off]);
        }
    };

    f32x16 acc[NOT] = {};
    float m_run = -__builtin_inff(), l_run = 0.f;

    // ---- prologue: buf0 ready; buf1 in flight; QK(0) computed ----
    stageK(0, 0); stageV(0, 0);
    __syncthreads();
    if (NT > 1) { stageK(1, 1); stageV(1, 1); }
    f32x16 scn0 = {}, scn1 = {};
    {
        const char* Kc = (const char*)&KT[0][0];
#pragma unroll
        for (int kk = 0; kk < 16; kk += 2) {
            bf16x8 kf0 = *reinterpret_cast<const bf16x8*>(Kc + kk * 1024 + hi * 512 + lo32 * 16);
            bf16x8 kf1 = *reinterpret_cast<const bf16x8*>(Kc + (kk + 1) * 1024 + hi * 512 + lo32 * 16);
            scn0 = MFMA32(kf0, qf[kk], scn0, 0, 0, 0);
            scn1 = MFMA32(kf1, qf[kk + 1], scn1, 0, 0, 0);
        }
    }
    unsigned long long mc0 = mrow[0], mc1 = mrow[1], mc2 = mrow[2], mc3 = mrow[3];
    __syncthreads();   // buf1 ready

    int ib_pv = 0, ib_qk = 1, ib_st = 2;

#pragma unroll 1
    for (int cc = 0; cc < NC; ++cc) {
        // prefetch next chunk's mask words (consumed 8 tiles later)
        unsigned long long mn0 = 0, mn1 = 0, mn2 = 0, mn3 = 0;
        if (cc + 1 < NC) {
            mn0 = mrow[(cc + 1) * 4 + 0]; mn1 = mrow[(cc + 1) * 4 + 1];
            mn2 = mrow[(cc + 1) * 4 + 2]; mn3 = mrow[(cc + 1) * 4 + 3];
        }

#pragma unroll 1
        for (int t8 = 0; t8 < 8; ++t8) {
            const int tt = cc * 8 + t8;

            // ---- collapse previous QK pair into current scores ----
            f32x16 scc;
#pragma unroll
            for (int r = 0; r < 16; ++r) scc[r] = scn0[r] + scn1[r];

            // ---- stage(t+2) ----
            if (tt + 2 < NT) { stageK(ib_st, tt + 2); stageV(ib_st, tt + 2); }

            // ---- QK(t+1): MFMA, independent of softmax(t) ----
            scn0 = (f32x16){}; scn1 = (f32x16){};
            if (tt + 1 < NT) {
                const char* Kc = (const char*)&KT[ib_qk][0];
#pragma unroll
                for (int kk = 0; kk < 16; kk += 2) {
                    bf16x8 kf0 = *reinterpret_cast<const bf16x8*>(Kc + kk * 1024 + hi * 512 + lo32 * 16);
                    bf16x8 kf1 = *reinterpret_cast<const bf16x8*>(Kc + (kk + 1) * 1024 + hi * 512 + lo32 * 16);
                    scn0 = MFMA32(kf0, qf[kk], scn0, 0, 0, 0);
                    scn1 = MFMA32(kf1, qf[kk + 1], scn1, 0, 0, 0);
                }
            }

            // ---- mask (u64 bit-extract) + online softmax (defer-max) ----
            const int shift = (t8 << 3) + hi;
            const unsigned long long mb0 = mc0 >> shift;
            const unsigned long long mb1 = mc1 >> shift;
            const unsigned long long mb2 = mc2 >> shift;
            const unsigned long long mb3 = mc3 >> shift;
            float p[16];
            float tmax = -__builtin_inff();
#pragma unroll
            for (int gg = 0; gg < 4; ++gg) {
                const int sh2 = 2 * gg;
                float s0v = scc[gg * 4 + 0] * SC;
                float s1v = scc[gg * 4 + 1] * SC;
                float s2v = scc[gg * 4 + 2] * SC;
                float s3v = scc[gg * 4 + 3] * SC;
                s0v = ((mb0 >> sh2) & 1ULL) ? s0v : -1e9f;
                s1v = ((mb1 >> sh2) & 1ULL) ? s1v : -1e9f;
                s2v = ((mb2 >> sh2) & 1ULL) ? s2v : -1e9f;
                s3v = ((mb3 >> sh2) & 1ULL) ? s3v : -1e9f;
                p[gg * 4 + 0] = s0v; p[gg * 4 + 1] = s1v;
                p[gg * 4 + 2] = s2v; p[gg * 4 + 3] = s3v;
                tmax = fmaxf(tmax, fmaxf(fmaxf(s0v, s1v), fmaxf(s2v, s3v)));
            }
            tmax = fmaxf(tmax, __shfl_xor(tmax, 32));
            if (!__all(tmax <= m_run + 8.0f)) {
                const float m_new = fmaxf(m_run, tmax);
                const float scale = exp2f((m_run - m_new) * L2E);
#pragma unroll
                for (int ot = 0; ot < NOT; ++ot)
#pragma unroll
                    for (int r = 0; r < 16; ++r) acc[ot][r] *= scale;
                l_run *= scale;
                m_run = m_new;
            }
            float psum = 0.f;
#pragma unroll
            for (int r2 = 0; r2 < 16; ++r2) {
                float pe = exp2f((p[r2] - m_run) * L2E);
                p[r2] = pe;
                psum += pe;
            }
            psum += __shfl_xor(psum, 32);
            l_run += psum;

            // ---- P -> B-frags in-register ----
            unsigned int c0 = cvtpk(p[0], p[1]),   c1 = cvtpk(p[2], p[3]);
            unsigned int c2 = cvtpk(p[4], p[5]),   c3 = cvtpk(p[6], p[7]);
            plswap(c0, c2); plswap(c1, c3);
            unsigned int c4 = cvtpk(p[8], p[9]),   c5 = cvtpk(p[10], p[11]);
            unsigned int c6 = cvtpk(p[12], p[13]), c7 = cvtpk(p[14], p[15]);
            plswap(c4, c6); plswap(c5, c7);
            const bf16x8 pf0 = mk8(c0, c1, c2, c3);
            const bf16x8 pf1 = mk8(c4, c5, c6, c7);

            // ---- PV(t): this wave's o-half ----
            const char* Vc = (const char*)&VTl[ib_pv][0];
#pragma unroll
            for (int ot = 0; ot < NOT; ++ot) {
                bf16x8 vf = *reinterpret_cast<const bf16x8*>(
                    Vc + hi * 4096 + (size_t)(obase + ot * 32 + lo32) * 16);
                acc[ot] = MFMA32(vf, pf0, acc[ot], 0, 0, 0);
            }
#pragma unroll
            for (int ot = 0; ot < NOT; ++ot) {
                bf16x8 vf = *reinterpret_cast<const bf16x8*>(
                    Vc + 8192 + hi * 4096 + (size_t)(obase + ot * 32 + lo32) * 16);
                acc[ot] = MFMA32(vf, pf1, acc[ot], 0, 0, 0);
            }

            __syncthreads();   // drains stage(t+2); rotate buffers
            const int tmp = ib_pv; ib_pv = ib_qk; ib_qk = ib_st; ib_st = tmp;
        }
        mc0 = mn0; mc1 = mn1; mc2 = mn2; mc3 = mn3;
    }

    // ---- epilogue: unnormalized bf16 partials + m/l ----
    const int qg = b * ND + qbase + lo32;
    unsigned short* pb = part + ((size_t)es0 * 16384 + qg) * 256;
#pragma unroll
    for (int ot = 0; ot < NOT; ++ot)
#pragma unroll
        for (int g2 = 0; g2 < 4; ++g2) {
            u32x2 pk;
            pk[0] = pack2(acc[ot][g2 * 4 + 0], acc[ot][g2 * 4 + 1]);
            pk[1] = pack2(acc[ot][g2 * 4 + 2], acc[ot][g2 * 4 + 3]);
            *reinterpret_cast<u32x2*>(pb + obase + ot * 32 + g2 * 8 + 4 * hi) = pk;
        }
    if (hi == 0 && side == 0) {
        mpart[(size_t)es0 * 16384 + qg] = m_run;
        lpart[(size_t)es0 * 16384 + qg] = l_run;
    }
}

// ---------------------------------------------------------------------------
// Kernel 3: fused combine + out-projection + residual + LayerNorm.
// ---------------------------------------------------------------------------
template<int ESP>
__global__ __launch_bounds__(256) void fuse_kernel(
    const unsigned short* __restrict__ part, const float* __restrict__ mpart,
    const float* __restrict__ lpart, const float* __restrict__ Wp,
    const float* __restrict__ bp, const float* __restrict__ x,
    const float* __restrict__ gamma, const float* __restrict__ beta,
    float* __restrict__ out)
{
    __shared__ unsigned short Xt[64][264];
    __shared__ unsigned short Wt[64][264];
    __shared__ float hL[64][264];
    __shared__ float cel[64][ESP];

    const int M0 = blockIdx.x * 64;
    const int t = threadIdx.x;
    const float L2E = 1.44269504f;

    if (t < 64) {
        float me[ESP], le[ESP], M = -__builtin_inff();
#pragma unroll
        for (int e = 0; e < ESP; ++e) {
            me[e] = mpart[(size_t)e * 16384 + M0 + t];
            le[e] = lpart[(size_t)e * 16384 + M0 + t];
            M = fmaxf(M, me[e]);
        }
        float wsum = 0.f;
#pragma unroll
        for (int e = 0; e < ESP; ++e) { me[e] = exp2f((me[e] - M) * L2E); wsum += me[e] * le[e]; }
        const float inv = 1.f / wsum;
#pragma unroll
        for (int e = 0; e < ESP; ++e) cel[t][e] = me[e] * inv;
    }
#pragma unroll
    for (int i = 0; i < 16; ++i) {
        int fidx = i * 256 + t, row = fidx >> 6, c4 = fidx & 63;
        f32x4 vW = *reinterpret_cast<const f32x4*>(Wp + (size_t)row * NH + c4 * 4);
        u32x2 pw; pw[0] = pack2(vW[0], vW[1]); pw[1] = pack2(vW[2], vW[3]);
        *reinterpret_cast<u32x2*>(&Wt[row][c4 * 4]) = pw;
    }
    __syncthreads();

#pragma unroll
    for (int i = 0; i < 8; ++i) {
        int fidx = i * 256 + t, row = fidx >> 5, c8 = fidx & 31;
        float o[8] = {};
#pragma unroll
        for (int e = 0; e < ESP; ++e) {
            u32x4 v = *reinterpret_cast<const u32x4*>(
                part + (((size_t)e * 16384 + M0 + row) * 256 + c8 * 8));
            const float ce = cel[row][e];
#pragma unroll
            for (int j = 0; j < 4; ++j) {
                o[2 * j]     += ce * bflo(v[j]);
                o[2 * j + 1] += ce * bfhi(v[j]);
            }
        }
        u32x4 pk;
#pragma unroll
        for (int j = 0; j < 4; ++j) pk[j] = pack2(o[2 * j], o[2 * j + 1]);
        *reinterpret_cast<u32x4*>(&Xt[row][c8 * 8]) = pk;
    }
    __syncthreads();

    const int w = t >> 6, lane = t & 63, lr = lane & 15, half = lane >> 4;
    const int ar0 = 32 * (w >> 1), br0 = 32 * (w & 1);

    for (int pc = 0; pc < 4; ++pc) {
        f32x4 acc[2][2] = {};
#pragma unroll
        for (int kk = 0; kk < 8; ++kk) {
            bf16x8 a[2], bfr[2];
#pragma unroll
            for (int f = 0; f < 2; ++f) {
                a[f]   = *reinterpret_cast<const bf16x8*>(&Wt[ar0 + 16 * f + lr][32 * kk + 8 * half]);
                bfr[f] = *reinterpret_cast<const bf16x8*>(&Xt[br0 + 16 * f + lr][32 * kk + 8 * half]);
            }
#pragma unroll
            for (int fa = 0; fa < 2; ++fa)
#pragma unroll
                for (int fb = 0; fb < 2; ++fb)
                    acc[fa][fb] = MFMA16(a[fa], bfr[fb], acc[fa][fb], 0, 0, 0);
        }
#pragma unroll
        for (int fa = 0; fa < 2; ++fa)
#pragma unroll
            for (int fb = 0; fb < 2; ++fb) {
                int p = pc * 64 + ar0 + 16 * fa + 4 * half;
                int m = br0 + 16 * fb + lr;
                *reinterpret_cast<f32x4*>(&hL[m][p]) = acc[fa][fb];
            }
        if (pc < 3) {
            __syncthreads();
#pragma unroll
            for (int i = 0; i < 16; ++i) {
                int fidx = i * 256 + t, row = fidx >> 6, c4 = fidx & 63;
                f32x4 vW = *reinterpret_cast<const f32x4*>(
                    Wp + (size_t)((pc + 1) * 64 + row) * NH + c4 * 4);
                u32x2 pw; pw[0] = pack2(vW[0], vW[1]); pw[1] = pack2(vW[2], vW[3]);
                *reinterpret_cast<u32x2*>(&Wt[row][c4 * 4]) = pw;
            }
            __syncthreads();
        }
    }
    __syncthreads();

    f32x4 gm = *reinterpret_cast<const f32x4*>(gamma + lane * 4);
    f32x4 be = *reinterpret_cast<const f32x4*>(beta + lane * 4);
    f32x4 bv = *reinterpret_cast<const f32x4*>(bp + lane * 4);
    for (int rr = 0; rr < 16; ++rr) {
        const int row = w * 16 + rr;
        f32x4 v = *reinterpret_cast<const f32x4*>(&hL[row][lane * 4]);
        f32x4 xr = *reinterpret_cast<const f32x4*>(x + (size_t)(M0 + row) * NH + lane * 4);
#pragma unroll
        for (int r = 0; r < 4; ++r) v[r] += xr[r] + bv[r];
        float s = v[0] + v[1] + v[2] + v[3];
#pragma unroll
        for (int off = 1; off < 64; off <<= 1) s += __shfl_xor(s, off);
        const float mu = s * (1.f / 256.f);
        f32x4 dv; float q = 0.f;
#pragma unroll
        for (int r = 0; r < 4; ++r) { dv[r] = v[r] - mu; q += dv[r] * dv[r]; }
#pragma unroll
        for (int off = 1; off < 64; off <<= 1) q += __shfl_xor(q, off);
        const float rs = rsqrtf(q * (1.f / 256.f) + 1e-5f);
        f32x4 o;
#pragma unroll
        for (int r = 0; r < 4; ++r) o[r] = dv[r] * rs * gm[r] + be[r];
        *reinterpret_cast<f32x4*>(out + (size_t)(M0 + row) * NH + lane * 4) = o;
    }
}

extern "C" void kernel_launch(void* const* d_in, const int* in_sizes, int n_in,
                              void* d_out, int out_size, void* d_ws, size_t ws_size,
                              hipStream_t stream)
{
    const float* x     = (const float*)d_in[0];
    const int*   adj   = (const int*)d_in[1];
    const float* Wq    = (const float*)d_in[2];
    const float* Wk    = (const float*)d_in[3];
    const float* Wv    = (const float*)d_in[4];
    const float* Wp    = (const float*)d_in[5];
    const float* bp    = (const float*)d_in[6];
    const float* gamma = (const float*)d_in[7];
    const float* beta  = (const float*)d_in[8];

    char* ws = (char*)d_ws;
    const size_t MB = 1024 * 1024;
    unsigned short* qb    = (unsigned short*)(ws);
    unsigned short* kb    = (unsigned short*)(ws + 8 * MB);
    unsigned short* vT    = (unsigned short*)(ws + 16 * MB);
    unsigned short* partb = (unsigned short*)(ws + 24 * MB);
    float* out = (float*)d_out;

    const bool big = ws_size >= (size_t)62 * MB;
    if (big) {
        float* mpart = (float*)(ws + 56 * MB);
        float* lpart = (float*)(ws + 56 * MB + 256 * 1024);
        unsigned long long* maskb = (unsigned long long*)(ws + 57 * MB);
        prep_kernel<<<dim3(768), 256, 0, stream>>>(x, Wq, Wk, Wv, adj, qb, kb, vT, maskb);
        attn_kernel<4><<<dim3(512), 512, 0, stream>>>(qb, kb, vT, maskb, partb, mpart, lpart);
        fuse_kernel<4><<<dim3(256), 256, 0, stream>>>(partb, mpart, lpart, Wp, bp, x, gamma, beta, out);
    } else {
        float* mpart = (float*)(ws + 40 * MB);
        float* lpart = (float*)(ws + 40 * MB + 128 * 1024);
        unsigned long long* maskb = (unsigned long long*)(ws + 41 * MB);
        prep_kernel<<<dim3(768), 256, 0, stream>>>(x, Wq, Wk, Wv, adj, qb, kb, vT, maskb);
        attn_kernel<2><<<dim3(256), 512, 0, stream>>>(qb, kb, vT, maskb, partb, mpart, lpart);
        fuse_kernel<2><<<dim3(256), 256, 0, stream>>>(partb, mpart, lpart, Wp, bp, x, gamma, beta, out);
    }
}

// Round 14
// 165.422 us; speedup vs baseline: 1.0579x; 1.0018x over previous
//
#include <hip/hip_runtime.h>
#include <stdint.h>

#define NB 8
#define ND 2048
#define NH 256

typedef __attribute__((ext_vector_type(8))) short bf16x8;
typedef __attribute__((ext_vector_type(4))) float f32x4;
typedef __attribute__((ext_vector_type(16))) float f32x16;
typedef __attribute__((ext_vector_type(4))) int   i32x4;
typedef __attribute__((ext_vector_type(2))) unsigned int u32x2;
typedef __attribute__((ext_vector_type(4))) unsigned int u32x4;

#define MFMA16 __builtin_amdgcn_mfma_f32_16x16x32_bf16
#define MFMA32 __builtin_amdgcn_mfma_f32_32x32x16_bf16

__device__ __forceinline__ unsigned short f2bf(float f) {
    union { float f; unsigned int u; } c; c.f = f;
    unsigned int u = c.u + 0x7FFFu + ((c.u >> 16) & 1u);
    return (unsigned short)(u >> 16);
}
__device__ __forceinline__ unsigned int pack2(float a, float b) {
    return (unsigned int)f2bf(a) | ((unsigned int)f2bf(b) << 16);
}
__device__ __forceinline__ unsigned int cvtpk(float a, float b) {
    unsigned int r;
    asm("v_cvt_pk_bf16_f32 %0, %1, %2" : "=v"(r) : "v"(a), "v"(b));
    return r;
}
__device__ __forceinline__ void plswap(unsigned int& a, unsigned int& b) {
    asm volatile("v_permlane32_swap_b32 %0, %1" : "+v"(a), "+v"(b));
}
__device__ __forceinline__ bf16x8 mk8(unsigned int a, unsigned int b, unsigned int c, unsigned int d) {
    union { unsigned int u[4]; bf16x8 v; } x;
    x.u[0] = a; x.u[1] = b; x.u[2] = c; x.u[3] = d;
    return x.v;
}
__device__ __forceinline__ void gload_lds16(const void* g, void* l) {
    __builtin_amdgcn_global_load_lds(
        (const __attribute__((address_space(1))) void*)g,
        (__attribute__((address_space(3))) void*)l, 16, 0, 0);
}
__device__ __forceinline__ float bflo(unsigned int u) { return __uint_as_float(u << 16); }
__device__ __forceinline__ float bfhi(unsigned int u) { return __uint_as_float(u & 0xffff0000u); }

// spread 8 bits: bit q -> bit 4q
__device__ __forceinline__ unsigned int spread8(unsigned int x) {
    x = (x | (x << 12)) & 0x000F000Fu;
    x = (x | (x << 6))  & 0x03030303u;
    x = (x | (x << 3))  & 0x11111111u;
    return x;
}

// ---------------------------------------------------------------------------
// Kernel 1: qkv (x staged ONCE per m-tile) + adj->mask32 pack.
//   grid 768: bid%3==0 -> qkv (256 blocks), else pack (512 blocks).
//   q row-major; kb[b][koct 32][e 2048][8]; vT[b][eoct 256][o 256][8]
//   mask32[(b*64 + tile)*2048 + row_local] u32: bit j = adj[row][tile*32+j]>0
//   Pack: i32x4 loads (16 in flight) -> ballots -> lanes 0-7 bit-transpose
//   each tile's u32 word via spread8.
// ---------------------------------------------------------------------------
__global__ __launch_bounds__(256) void prep_kernel(
    const float* __restrict__ x,
    const float* __restrict__ Wq, const float* __restrict__ Wk, const float* __restrict__ Wv,
    const int* __restrict__ adj,
    unsigned short* __restrict__ qb, unsigned short* __restrict__ kb,
    unsigned short* __restrict__ vT, unsigned int* __restrict__ mask32)
{
    __shared__ unsigned short Wt[64][264];
    __shared__ unsigned short Xt[64][264];

    const int bid = blockIdx.x;
    const int r3 = bid % 3, q3 = bid / 3;
    const int t = threadIdx.x;

    if (r3 != 0) {
        // ---- pack: 512 blocks, 4 waves, 8 rows/wave, 16 x 16B loads in flight ----
        const int pi = q3 * 2 + (r3 - 1);        // 0..511
        const int w = t >> 6, l = t & 63;
        const int wave_id = pi * 4 + w;          // 0..2047
#pragma unroll 1
        for (int k = 0; k < 8; k += 2) {
            const int row0 = wave_id + k * 2048;
            const int row1 = wave_id + (k + 1) * 2048;
            const int* ar0_ = adj + (size_t)row0 * ND;
            const int* ar1_ = adj + (size_t)row1 * ND;
            i32x4 v0[8], v1[8];
#pragma unroll
            for (int cc = 0; cc < 8; ++cc)
                v0[cc] = *reinterpret_cast<const i32x4*>(ar0_ + cc * 256 + l * 4);
#pragma unroll
            for (int cc = 0; cc < 8; ++cc)
                v1[cc] = *reinterpret_cast<const i32x4*>(ar1_ + cc * 256 + l * 4);

            const int bb0 = row0 >> 11, rl0 = row0 & 2047;
            const int bb1 = row1 >> 11, rl1 = row1 & 2047;
#pragma unroll
            for (int cc = 0; cc < 8; ++cc) {
                unsigned long long ba[4];
                ba[0] = __ballot(v0[cc][0] > 0);
                ba[1] = __ballot(v0[cc][1] > 0);
                ba[2] = __ballot(v0[cc][2] > 0);
                ba[3] = __ballot(v0[cc][3] > 0);
                if (l < 8) {
                    unsigned int wd = 0;
#pragma unroll
                    for (int r = 0; r < 4; ++r)
                        wd |= spread8((unsigned int)((ba[r] >> (l * 8)) & 0xFFull)) << r;
                    mask32[((size_t)bb0 * 64 + cc * 8 + l) * 2048 + rl0] = wd;
                }
            }
#pragma unroll
            for (int cc = 0; cc < 8; ++cc) {
                unsigned long long ba[4];
                ba[0] = __ballot(v1[cc][0] > 0);
                ba[1] = __ballot(v1[cc][1] > 0);
                ba[2] = __ballot(v1[cc][2] > 0);
                ba[3] = __ballot(v1[cc][3] > 0);
                if (l < 8) {
                    unsigned int wd = 0;
#pragma unroll
                    for (int r = 0; r < 4; ++r)
                        wd |= spread8((unsigned int)((ba[r] >> (l * 8)) & 0xFFull)) << r;
                    mask32[((size_t)bb1 * 64 + cc * 8 + l) * 2048 + rl1] = wd;
                }
            }
        }
        return;
    }

    // ---- qkv: 256 blocks; x staged once; 12 GEMM tiles (3 z x 4 o-chunks) ----
    const int m0 = q3 * 64;
    const int w = t >> 6, lane = t & 63, lr = lane & 15, half = lane >> 4;
    const int ar0 = 32 * (w >> 1), br0 = 32 * (w & 1);

#pragma unroll
    for (int i = 0; i < 16; ++i) {
        int fidx = i * 256 + t, row = fidx >> 6, c4 = fidx & 63;
        f32x4 vX = *reinterpret_cast<const f32x4*>(x + (size_t)(m0 + row) * NH + c4 * 4);
        u32x2 px; px[0] = pack2(vX[0], vX[1]); px[1] = pack2(vX[2], vX[3]);
        *reinterpret_cast<u32x2*>(&Xt[row][c4 * 4]) = px;
    }

    for (int z = 0; z < 3; ++z) {
        const float* W = (z == 0) ? Wq : (z == 1 ? Wk : Wv);
        for (int oc = 0; oc < 4; ++oc) {
            const int o0 = oc * 64;
            __syncthreads();   // prior GEMM's Wt reads done (covers x-stage too)
#pragma unroll
            for (int i = 0; i < 16; ++i) {
                int fidx = i * 256 + t, row = fidx >> 6, c4 = fidx & 63;
                f32x4 vW = *reinterpret_cast<const f32x4*>(W + (size_t)(o0 + row) * NH + c4 * 4);
                u32x2 pw; pw[0] = pack2(vW[0], vW[1]); pw[1] = pack2(vW[2], vW[3]);
                *reinterpret_cast<u32x2*>(&Wt[row][c4 * 4]) = pw;
            }
            __syncthreads();

            const unsigned short (*Ab)[264] = (z == 2) ? Xt : Wt;
            const unsigned short (*Bb)[264] = (z == 2) ? Wt : Xt;

            f32x4 acc[2][2] = {};
#pragma unroll
            for (int kk = 0; kk < 8; ++kk) {
                bf16x8 a[2], bfr[2];
#pragma unroll
                for (int f = 0; f < 2; ++f) {
                    a[f]   = *reinterpret_cast<const bf16x8*>(&Ab[ar0 + 16 * f + lr][32 * kk + 8 * half]);
                    bfr[f] = *reinterpret_cast<const bf16x8*>(&Bb[br0 + 16 * f + lr][32 * kk + 8 * half]);
                }
#pragma unroll
                for (int fa = 0; fa < 2; ++fa)
#pragma unroll
                    for (int fb = 0; fb < 2; ++fb)
                        acc[fa][fb] = MFMA16(a[fa], bfr[fb], acc[fa][fb], 0, 0, 0);
            }

            if (z == 0) {
#pragma unroll
                for (int fa = 0; fa < 2; ++fa)
#pragma unroll
                    for (int fb = 0; fb < 2; ++fb) {
                        int m = m0 + br0 + 16 * fb + lr;
                        int o = o0 + ar0 + 16 * fa + 4 * half;
                        u32x2 pk; pk[0] = pack2(acc[fa][fb][0], acc[fa][fb][1]);
                        pk[1] = pack2(acc[fa][fb][2], acc[fa][fb][3]);
                        *reinterpret_cast<u32x2*>(qb + (size_t)m * NH + o) = pk;
                    }
            } else if (z == 1) {
#pragma unroll
                for (int fa = 0; fa < 2; ++fa)
#pragma unroll
                    for (int fb = 0; fb < 2; ++fb) {
                        int m = m0 + br0 + 16 * fb + lr;          // token e
                        int o = o0 + ar0 + 16 * fa + 4 * half;    // k-feature
                        int bb = m >> 11, el = m & 2047;
                        u32x2 pk; pk[0] = pack2(acc[fa][fb][0], acc[fa][fb][1]);
                        pk[1] = pack2(acc[fa][fb][2], acc[fa][fb][3]);
                        size_t idx = (((size_t)bb * 32 + (o >> 3)) * 2048 + el) * 8 + (o & 7);
                        *reinterpret_cast<u32x2*>(kb + idx) = pk;
                    }
            } else {
#pragma unroll
                for (int fa = 0; fa < 2; ++fa)
#pragma unroll
                    for (int fb = 0; fb < 2; ++fb) {
                        int dg = m0 + ar0 + 16 * fa + 4 * half;   // token e
                        int o  = o0 + br0 + 16 * fb + lr;         // out feature
                        int bb = dg >> 11, el = dg & 2047;
                        u32x2 pk; pk[0] = pack2(acc[fa][fb][0], acc[fa][fb][1]);
                        pk[1] = pack2(acc[fa][fb][2], acc[fa][fb][3]);
                        size_t idx = (((size_t)bb * 256 + (el >> 3)) * 256 + o) * 8 + (el & 7);
                        *reinterpret_cast<u32x2*>(vT + idx) = pk;
                    }
            }
        }
    }
}

// ---------------------------------------------------------------------------
// Kernel 2: flash attention partials, software-pipelined (R12-proven):
// triple-buffered K/V (96KB LDS); per tile: stage(t+2) || QK(t+1) [MFMA]
// || softmax(t) [VALU under QK] || PV(t). One barrier/tile.
// mask32: one coalesced u32 load per tile, prefetched one tile ahead.
// 8 waves; pair shares 32 q-rows (QK dup), PV split by o-half (acc[4]).
// ---------------------------------------------------------------------------
template<int ESP>
__global__ __launch_bounds__(512, 2) void attn_kernel(
    const unsigned short* __restrict__ qb, const unsigned short* __restrict__ kb,
    const unsigned short* __restrict__ vT, const unsigned int* __restrict__ mask32,
    unsigned short* __restrict__ part, float* __restrict__ mpart, float* __restrict__ lpart)
{
    constexpr int QB = 128;                  // q-rows per block
    constexpr int NOT = 4;                   // 32-o tiles per wave (o-half)
    constexpr int NT = (ND / ESP) / 32;      // 32-e tiles per block

    __shared__ unsigned char KT[3][16384];   // [koct 32][e 32][16B]
    __shared__ unsigned char VTl[3][16384];  // [eoct 4][o 256][16B]

    const int bid = blockIdx.x;
    const int b = bid & 7, es0 = (bid >> 3) & (ESP - 1), qt = bid / (8 * ESP);
    const int t = threadIdx.x, w = t >> 6, l = t & 63;
    const int lo32 = l & 31, hi = l >> 5;
    const int g = w & 3, side = w >> 2;
    const int qbase = qt * QB + g * 32;
    const int obase = side * 128;
    const int ebase = es0 * (ND / ESP);
    const float SC = 0.0625f, L2E = 1.44269504f;

    bf16x8 qf[16];
    {
        const unsigned short* qr = qb + ((size_t)b * ND + qbase + lo32) * NH + 8 * hi;
#pragma unroll
        for (int kk = 0; kk < 16; ++kk)
            qf[kk] = *reinterpret_cast<const bf16x8*>(qr + kk * 16);
    }

    const char* kbc = (const char*)kb + ((size_t)b << 20);
    const char* vtc = (const char*)vT + ((size_t)b << 20);
    const unsigned int* mrow =
        mask32 + ((size_t)b * 64 + es0 * NT) * 2048 + qbase + lo32;

    auto stageK = [&](int buf, int tt) {
        const int e0s = ebase + tt * 32;
#pragma unroll
        for (int i = 0; i < 2; ++i) {
            int off = i * 8192 + t * 16;
            int koct = off >> 9, e = (off >> 4) & 31;
            gload_lds16(kbc + (size_t)koct * 32768 + (size_t)(e0s + e) * 16, &KT[buf][off]);
        }
    };
    auto stageV = [&](int buf, int tt) {
        const int Eb = (ebase + tt * 32) >> 3;
#pragma unroll
        for (int i = 0; i < 2; ++i) {
            int off = i * 8192 + t * 16;
            int eoct = off >> 12, o = (off >> 4) & 255;
            gload_lds16(vtc + (size_t)(Eb + eoct) * 4096 + (size_t)o * 16, &VTl[buf][off]);
        }
    };

    f32x16 acc[NOT] = {};
    float m_run = -__builtin_inff(), l_run = 0.f;

    // ---- prologue: buf0 ready; buf1 in flight; QK(0) computed ----
    stageK(0, 0); stageV(0, 0);
    __syncthreads();
    if (NT > 1) { stageK(1, 1); stageV(1, 1); }
    f32x16 scn0 = {}, scn1 = {};
    {
        const char* Kc = (const char*)&KT[0][0];
#pragma unroll
        for (int kk = 0; kk < 16; kk += 2) {
            bf16x8 kf0 = *reinterpret_cast<const bf16x8*>(Kc + kk * 1024 + hi * 512 + lo32 * 16);
            bf16x8 kf1 = *reinterpret_cast<const bf16x8*>(Kc + (kk + 1) * 1024 + hi * 512 + lo32 * 16);
            scn0 = MFMA32(kf0, qf[kk], scn0, 0, 0, 0);
            scn1 = MFMA32(kf1, qf[kk + 1], scn1, 0, 0, 0);
        }
    }
    unsigned int m_cur = mrow[0];
    __syncthreads();   // buf1 ready

    int ib_pv = 0, ib_qk = 1, ib_st = 2;

#pragma unroll 1
    for (int tt = 0; tt < NT; ++tt) {
        // ---- collapse previous QK pair into current scores ----
        f32x16 scc;
#pragma unroll
        for (int r = 0; r < 16; ++r) scc[r] = scn0[r] + scn1[r];

        // ---- stage(t+2) ----
        if (tt + 2 < NT) { stageK(ib_st, tt + 2); stageV(ib_st, tt + 2); }
        const unsigned int m_next = (tt + 1 < NT) ? mrow[(size_t)(tt + 1) * 2048] : 0u;

        // ---- QK(t+1): MFMA, independent of softmax(t) below ----
        scn0 = (f32x16){}; scn1 = (f32x16){};
        if (tt + 1 < NT) {
            const char* Kc = (const char*)&KT[ib_qk][0];
#pragma unroll
            for (int kk = 0; kk < 16; kk += 2) {
                bf16x8 kf0 = *reinterpret_cast<const bf16x8*>(Kc + kk * 1024 + hi * 512 + lo32 * 16);
                bf16x8 kf1 = *reinterpret_cast<const bf16x8*>(Kc + (kk + 1) * 1024 + hi * 512 + lo32 * 16);
                scn0 = MFMA32(kf0, qf[kk], scn0, 0, 0, 0);
                scn1 = MFMA32(kf1, qf[kk + 1], scn1, 0, 0, 0);
            }
        }

        // ---- mask + online softmax (defer-max) for tile t ----
        float p[16];
        float tmax = -__builtin_inff();
        const unsigned int mb = m_cur >> (4 * hi);
#pragma unroll
        for (int gg = 0; gg < 4; ++gg) {
            const unsigned int mg = mb >> (8 * gg);
#pragma unroll
            for (int r = 0; r < 4; ++r) {
                float sv = scc[gg * 4 + r] * SC;
                sv = ((mg >> r) & 1u) ? sv : -1e9f;
                p[gg * 4 + r] = sv;
                tmax = fmaxf(tmax, sv);
            }
        }
        tmax = fmaxf(tmax, __shfl_xor(tmax, 32));
        if (!__all(tmax <= m_run + 8.0f)) {
            const float m_new = fmaxf(m_run, tmax);
            const float scale = exp2f((m_run - m_new) * L2E);
#pragma unroll
            for (int ot = 0; ot < NOT; ++ot)
#pragma unroll
                for (int r = 0; r < 16; ++r) acc[ot][r] *= scale;
            l_run *= scale;
            m_run = m_new;
        }
        float psum = 0.f;
#pragma unroll
        for (int r2 = 0; r2 < 16; ++r2) {
            float pe = exp2f((p[r2] - m_run) * L2E);
            p[r2] = pe;
            psum += pe;
        }
        psum += __shfl_xor(psum, 32);
        l_run += psum;

        // ---- P -> B-frags in-register ----
        unsigned int c0 = cvtpk(p[0], p[1]),   c1 = cvtpk(p[2], p[3]);
        unsigned int c2 = cvtpk(p[4], p[5]),   c3 = cvtpk(p[6], p[7]);
        plswap(c0, c2); plswap(c1, c3);
        unsigned int c4 = cvtpk(p[8], p[9]),   c5 = cvtpk(p[10], p[11]);
        unsigned int c6 = cvtpk(p[12], p[13]), c7 = cvtpk(p[14], p[15]);
        plswap(c4, c6); plswap(c5, c7);
        const bf16x8 pf0 = mk8(c0, c1, c2, c3);
        const bf16x8 pf1 = mk8(c4, c5, c6, c7);

        // ---- PV(t): this wave's o-half ----
        const char* Vc = (const char*)&VTl[ib_pv][0];
#pragma unroll
        for (int ot = 0; ot < NOT; ++ot) {
            bf16x8 vf = *reinterpret_cast<const bf16x8*>(
                Vc + hi * 4096 + (size_t)(obase + ot * 32 + lo32) * 16);
            acc[ot] = MFMA32(vf, pf0, acc[ot], 0, 0, 0);
        }
#pragma unroll
        for (int ot = 0; ot < NOT; ++ot) {
            bf16x8 vf = *reinterpret_cast<const bf16x8*>(
                Vc + 8192 + hi * 4096 + (size_t)(obase + ot * 32 + lo32) * 16);
            acc[ot] = MFMA32(vf, pf1, acc[ot], 0, 0, 0);
        }

        __syncthreads();   // drains stage(t+2); buffers rotate safely
        m_cur = m_next;
        const int tmp = ib_pv; ib_pv = ib_qk; ib_qk = ib_st; ib_st = tmp;
    }

    // ---- epilogue: unnormalized bf16 partials + m/l ----
    const int qg = b * ND + qbase + lo32;
    unsigned short* pb = part + ((size_t)es0 * 16384 + qg) * 256;
#pragma unroll
    for (int ot = 0; ot < NOT; ++ot)
#pragma unroll
        for (int g2 = 0; g2 < 4; ++g2) {
            u32x2 pk;
            pk[0] = pack2(acc[ot][g2 * 4 + 0], acc[ot][g2 * 4 + 1]);
            pk[1] = pack2(acc[ot][g2 * 4 + 2], acc[ot][g2 * 4 + 3]);
            *reinterpret_cast<u32x2*>(pb + obase + ot * 32 + g2 * 8 + 4 * hi) = pk;
        }
    if (hi == 0 && side == 0) {
        mpart[(size_t)es0 * 16384 + qg] = m_run;
        lpart[(size_t)es0 * 16384 + qg] = l_run;
    }
}

// ---------------------------------------------------------------------------
// Kernel 3: fused combine + out-projection + residual + LayerNorm.
// ---------------------------------------------------------------------------
template<int ESP>
__global__ __launch_bounds__(256) void fuse_kernel(
    const unsigned short* __restrict__ part, const float* __restrict__ mpart,
    const float* __restrict__ lpart, const float* __restrict__ Wp,
    const float* __restrict__ bp, const float* __restrict__ x,
    const float* __restrict__ gamma, const float* __restrict__ beta,
    float* __restrict__ out)
{
    __shared__ unsigned short Xt[64][264];
    __shared__ unsigned short Wt[64][264];
    __shared__ float hL[64][264];
    __shared__ float cel[64][ESP];

    const int M0 = blockIdx.x * 64;
    const int t = threadIdx.x;
    const float L2E = 1.44269504f;

    if (t < 64) {
        float me[ESP], le[ESP], M = -__builtin_inff();
#pragma unroll
        for (int e = 0; e < ESP; ++e) {
            me[e] = mpart[(size_t)e * 16384 + M0 + t];
            le[e] = lpart[(size_t)e * 16384 + M0 + t];
            M = fmaxf(M, me[e]);
        }
        float wsum = 0.f;
#pragma unroll
        for (int e = 0; e < ESP; ++e) { me[e] = exp2f((me[e] - M) * L2E); wsum += me[e] * le[e]; }
        const float inv = 1.f / wsum;
#pragma unroll
        for (int e = 0; e < ESP; ++e) cel[t][e] = me[e] * inv;
    }
#pragma unroll
    for (int i = 0; i < 16; ++i) {
        int fidx = i * 256 + t, row = fidx >> 6, c4 = fidx & 63;
        f32x4 vW = *reinterpret_cast<const f32x4*>(Wp + (size_t)row * NH + c4 * 4);
        u32x2 pw; pw[0] = pack2(vW[0], vW[1]); pw[1] = pack2(vW[2], vW[3]);
        *reinterpret_cast<u32x2*>(&Wt[row][c4 * 4]) = pw;
    }
    __syncthreads();

#pragma unroll
    for (int i = 0; i < 8; ++i) {
        int fidx = i * 256 + t, row = fidx >> 5, c8 = fidx & 31;
        float o[8] = {};
#pragma unroll
        for (int e = 0; e < ESP; ++e) {
            u32x4 v = *reinterpret_cast<const u32x4*>(
                part + (((size_t)e * 16384 + M0 + row) * 256 + c8 * 8));
            const float ce = cel[row][e];
#pragma unroll
            for (int j = 0; j < 4; ++j) {
                o[2 * j]     += ce * bflo(v[j]);
                o[2 * j + 1] += ce * bfhi(v[j]);
            }
        }
        u32x4 pk;
#pragma unroll
        for (int j = 0; j < 4; ++j) pk[j] = pack2(o[2 * j], o[2 * j + 1]);
        *reinterpret_cast<u32x4*>(&Xt[row][c8 * 8]) = pk;
    }
    __syncthreads();

    const int w = t >> 6, lane = t & 63, lr = lane & 15, half = lane >> 4;
    const int ar0 = 32 * (w >> 1), br0 = 32 * (w & 1);

    for (int pc = 0; pc < 4; ++pc) {
        f32x4 acc[2][2] = {};
#pragma unroll
        for (int kk = 0; kk < 8; ++kk) {
            bf16x8 a[2], bfr[2];
#pragma unroll
            for (int f = 0; f < 2; ++f) {
                a[f]   = *reinterpret_cast<const bf16x8*>(&Wt[ar0 + 16 * f + lr][32 * kk + 8 * half]);
                bfr[f] = *reinterpret_cast<const bf16x8*>(&Xt[br0 + 16 * f + lr][32 * kk + 8 * half]);
            }
#pragma unroll
            for (int fa = 0; fa < 2; ++fa)
#pragma unroll
                for (int fb = 0; fb < 2; ++fb)
                    acc[fa][fb] = MFMA16(a[fa], bfr[fb], acc[fa][fb], 0, 0, 0);
        }
#pragma unroll
        for (int fa = 0; fa < 2; ++fa)
#pragma unroll
            for (int fb = 0; fb < 2; ++fb) {
                int p = pc * 64 + ar0 + 16 * fa + 4 * half;
                int m = br0 + 16 * fb + lr;
                *reinterpret_cast<f32x4*>(&hL[m][p]) = acc[fa][fb];
            }
        if (pc < 3) {
            __syncthreads();
#pragma unroll
            for (int i = 0; i < 16; ++i) {
                int fidx = i * 256 + t, row = fidx >> 6, c4 = fidx & 63;
                f32x4 vW = *reinterpret_cast<const f32x4*>(
                    Wp + (size_t)((pc + 1) * 64 + row) * NH + c4 * 4);
                u32x2 pw; pw[0] = pack2(vW[0], vW[1]); pw[1] = pack2(vW[2], vW[3]);
                *reinterpret_cast<u32x2*>(&Wt[row][c4 * 4]) = pw;
            }
            __syncthreads();
        }
    }
    __syncthreads();

    f32x4 gm = *reinterpret_cast<const f32x4*>(gamma + lane * 4);
    f32x4 be = *reinterpret_cast<const f32x4*>(beta + lane * 4);
    f32x4 bv = *reinterpret_cast<const f32x4*>(bp + lane * 4);
    for (int rr = 0; rr < 16; ++rr) {
        const int row = w * 16 + rr;
        f32x4 v = *reinterpret_cast<const f32x4*>(&hL[row][lane * 4]);
        f32x4 xr = *reinterpret_cast<const f32x4*>(x + (size_t)(M0 + row) * NH + lane * 4);
#pragma unroll
        for (int r = 0; r < 4; ++r) v[r] += xr[r] + bv[r];
        float s = v[0] + v[1] + v[2] + v[3];
#pragma unroll
        for (int off = 1; off < 64; off <<= 1) s += __shfl_xor(s, off);
        const float mu = s * (1.f / 256.f);
        f32x4 dv; float q = 0.f;
#pragma unroll
        for (int r = 0; r < 4; ++r) { dv[r] = v[r] - mu; q += dv[r] * dv[r]; }
#pragma unroll
        for (int off = 1; off < 64; off <<= 1) q += __shfl_xor(q, off);
        const float rs = rsqrtf(q * (1.f / 256.f) + 1e-5f);
        f32x4 o;
#pragma unroll
        for (int r = 0; r < 4; ++r) o[r] = dv[r] * rs * gm[r] + be[r];
        *reinterpret_cast<f32x4*>(out + (size_t)(M0 + row) * NH + lane * 4) = o;
    }
}

extern "C" void kernel_launch(void* const* d_in, const int* in_sizes, int n_in,
                              void* d_out, int out_size, void* d_ws, size_t ws_size,
                              hipStream_t stream)
{
    const float* x     = (const float*)d_in[0];
    const int*   adj   = (const int*)d_in[1];
    const float* Wq    = (const float*)d_in[2];
    const float* Wk    = (const float*)d_in[3];
    const float* Wv    = (const float*)d_in[4];
    const float* Wp    = (const float*)d_in[5];
    const float* bp    = (const float*)d_in[6];
    const float* gamma = (const float*)d_in[7];
    const float* beta  = (const float*)d_in[8];

    char* ws = (char*)d_ws;
    const size_t MB = 1024 * 1024;
    unsigned short* qb    = (unsigned short*)(ws);
    unsigned short* kb    = (unsigned short*)(ws + 8 * MB);
    unsigned short* vT    = (unsigned short*)(ws + 16 * MB);
    unsigned short* partb = (unsigned short*)(ws + 24 * MB);
    float* out = (float*)d_out;

    const bool big = ws_size >= (size_t)62 * MB;
    if (big) {
        float* mpart = (float*)(ws + 56 * MB);
        float* lpart = (float*)(ws + 56 * MB + 256 * 1024);
        unsigned int* mask32 = (unsigned int*)(ws + 57 * MB);
        prep_kernel<<<dim3(768), 256, 0, stream>>>(x, Wq, Wk, Wv, adj, qb, kb, vT, mask32);
        attn_kernel<4><<<dim3(512), 512, 0, stream>>>(qb, kb, vT, mask32, partb, mpart, lpart);
        fuse_kernel<4><<<dim3(256), 256, 0, stream>>>(partb, mpart, lpart, Wp, bp, x, gamma, beta, out);
    } else {
        float* mpart = (float*)(ws + 40 * MB);
        float* lpart = (float*)(ws + 40 * MB + 128 * 1024);
        unsigned int* mask32 = (unsigned int*)(ws + 41 * MB);
        prep_kernel<<<dim3(768), 256, 0, stream>>>(x, Wq, Wk, Wv, adj, qb, kb, vT, mask32);
        attn_kernel<2><<<dim3(256), 512, 0, stream>>>(qb, kb, vT, mask32, partb, mpart, lpart);
        fuse_kernel<2><<<dim3(256), 256, 0, stream>>>(partb, mpart, lpart, Wp, bp, x, gamma, beta, out);
    }
}

// Round 15
// 133.034 us; speedup vs baseline: 1.3154x; 1.2435x over previous
//
#include <hip/hip_runtime.h>
#include <stdint.h>

#define NB 8
#define ND 2048
#define NH 256

typedef __attribute__((ext_vector_type(8))) short bf16x8;
typedef __attribute__((ext_vector_type(4))) float f32x4;
typedef __attribute__((ext_vector_type(16))) float f32x16;
typedef __attribute__((ext_vector_type(4))) int   i32x4;
typedef __attribute__((ext_vector_type(2))) unsigned int u32x2;
typedef __attribute__((ext_vector_type(4))) unsigned int u32x4;

#define MFMA16 __builtin_amdgcn_mfma_f32_16x16x32_bf16
#define MFMA32 __builtin_amdgcn_mfma_f32_32x32x16_bf16

__device__ __forceinline__ unsigned short f2bf(float f) {
    union { float f; unsigned int u; } c; c.f = f;
    unsigned int u = c.u + 0x7FFFu + ((c.u >> 16) & 1u);
    return (unsigned short)(u >> 16);
}
__device__ __forceinline__ unsigned int pack2(float a, float b) {
    return (unsigned int)f2bf(a) | ((unsigned int)f2bf(b) << 16);
}
__device__ __forceinline__ unsigned int cvtpk(float a, float b) {
    unsigned int r;
    asm("v_cvt_pk_bf16_f32 %0, %1, %2" : "=v"(r) : "v"(a), "v"(b));
    return r;
}
__device__ __forceinline__ void plswap(unsigned int& a, unsigned int& b) {
    asm volatile("v_permlane32_swap_b32 %0, %1" : "+v"(a), "+v"(b));
}
__device__ __forceinline__ bf16x8 mk8(unsigned int a, unsigned int b, unsigned int c, unsigned int d) {
    union { unsigned int u[4]; bf16x8 v; } x;
    x.u[0] = a; x.u[1] = b; x.u[2] = c; x.u[3] = d;
    return x.v;
}
__device__ __forceinline__ void gload_lds16(const void* g, void* l) {
    __builtin_amdgcn_global_load_lds(
        (const __attribute__((address_space(1))) void*)g,
        (__attribute__((address_space(3))) void*)l, 16, 0, 0);
}
__device__ __forceinline__ float bflo(unsigned int u) { return __uint_as_float(u << 16); }
__device__ __forceinline__ float bfhi(unsigned int u) { return __uint_as_float(u & 0xffff0000u); }

// spread 8 bits: bit q -> bit 4q
__device__ __forceinline__ unsigned int spread8(unsigned int x) {
    x = (x | (x << 12)) & 0x000F000Fu;
    x = (x | (x << 6))  & 0x03030303u;
    x = (x | (x << 3))  & 0x11111111u;
    return x;
}

// ---------------------------------------------------------------------------
// Kernel 1: qkv (x staged ONCE per m-tile) + adj->mask32 pack.
//   grid 768: bid%3==0 -> qkv (256 blocks), else pack (512 blocks).
//   q row-major; kb[b][koct 32][e 2048][8]; vT[b][eoct 256][o 256][8]
//   mask32[(b*64 + tile)*2048 + row_local] u32: bit j = adj[row][tile*32+j]>0
// ---------------------------------------------------------------------------
__global__ __launch_bounds__(256) void prep_kernel(
    const float* __restrict__ x,
    const float* __restrict__ Wq, const float* __restrict__ Wk, const float* __restrict__ Wv,
    const int* __restrict__ adj,
    unsigned short* __restrict__ qb, unsigned short* __restrict__ kb,
    unsigned short* __restrict__ vT, unsigned int* __restrict__ mask32)
{
    __shared__ unsigned short Wt[64][264];
    __shared__ unsigned short Xt[64][264];

    const int bid = blockIdx.x;
    const int r3 = bid % 3, q3 = bid / 3;
    const int t = threadIdx.x;

    if (r3 != 0) {
        // ---- pack: 512 blocks, 4 waves, 8 rows/wave, 16 x 16B loads in flight ----
        const int pi = q3 * 2 + (r3 - 1);        // 0..511
        const int w = t >> 6, l = t & 63;
        const int wave_id = pi * 4 + w;          // 0..2047
#pragma unroll 1
        for (int k = 0; k < 8; k += 2) {
            const int row0 = wave_id + k * 2048;
            const int row1 = wave_id + (k + 1) * 2048;
            const int* ar0_ = adj + (size_t)row0 * ND;
            const int* ar1_ = adj + (size_t)row1 * ND;
            i32x4 v0[8], v1[8];
#pragma unroll
            for (int cc = 0; cc < 8; ++cc)
                v0[cc] = *reinterpret_cast<const i32x4*>(ar0_ + cc * 256 + l * 4);
#pragma unroll
            for (int cc = 0; cc < 8; ++cc)
                v1[cc] = *reinterpret_cast<const i32x4*>(ar1_ + cc * 256 + l * 4);

            const int bb0 = row0 >> 11, rl0 = row0 & 2047;
            const int bb1 = row1 >> 11, rl1 = row1 & 2047;
#pragma unroll
            for (int cc = 0; cc < 8; ++cc) {
                unsigned long long ba[4];
                ba[0] = __ballot(v0[cc][0] > 0);
                ba[1] = __ballot(v0[cc][1] > 0);
                ba[2] = __ballot(v0[cc][2] > 0);
                ba[3] = __ballot(v0[cc][3] > 0);
                if (l < 8) {
                    unsigned int wd = 0;
#pragma unroll
                    for (int r = 0; r < 4; ++r)
                        wd |= spread8((unsigned int)((ba[r] >> (l * 8)) & 0xFFull)) << r;
                    mask32[((size_t)bb0 * 64 + cc * 8 + l) * 2048 + rl0] = wd;
                }
            }
#pragma unroll
            for (int cc = 0; cc < 8; ++cc) {
                unsigned long long ba[4];
                ba[0] = __ballot(v1[cc][0] > 0);
                ba[1] = __ballot(v1[cc][1] > 0);
                ba[2] = __ballot(v1[cc][2] > 0);
                ba[3] = __ballot(v1[cc][3] > 0);
                if (l < 8) {
                    unsigned int wd = 0;
#pragma unroll
                    for (int r = 0; r < 4; ++r)
                        wd |= spread8((unsigned int)((ba[r] >> (l * 8)) & 0xFFull)) << r;
                    mask32[((size_t)bb1 * 64 + cc * 8 + l) * 2048 + rl1] = wd;
                }
            }
        }
        return;
    }

    // ---- qkv: 256 blocks; x staged once; 12 GEMM tiles (3 z x 4 o-chunks) ----
    const int m0 = q3 * 64;
    const int w = t >> 6, lane = t & 63, lr = lane & 15, half = lane >> 4;
    const int ar0 = 32 * (w >> 1), br0 = 32 * (w & 1);

#pragma unroll
    for (int i = 0; i < 16; ++i) {
        int fidx = i * 256 + t, row = fidx >> 6, c4 = fidx & 63;
        f32x4 vX = *reinterpret_cast<const f32x4*>(x + (size_t)(m0 + row) * NH + c4 * 4);
        u32x2 px; px[0] = pack2(vX[0], vX[1]); px[1] = pack2(vX[2], vX[3]);
        *reinterpret_cast<u32x2*>(&Xt[row][c4 * 4]) = px;
    }

    for (int z = 0; z < 3; ++z) {
        const float* W = (z == 0) ? Wq : (z == 1 ? Wk : Wv);
        for (int oc = 0; oc < 4; ++oc) {
            const int o0 = oc * 64;
            __syncthreads();   // prior GEMM's Wt reads done (covers x-stage too)
#pragma unroll
            for (int i = 0; i < 16; ++i) {
                int fidx = i * 256 + t, row = fidx >> 6, c4 = fidx & 63;
                f32x4 vW = *reinterpret_cast<const f32x4*>(W + (size_t)(o0 + row) * NH + c4 * 4);
                u32x2 pw; pw[0] = pack2(vW[0], vW[1]); pw[1] = pack2(vW[2], vW[3]);
                *reinterpret_cast<u32x2*>(&Wt[row][c4 * 4]) = pw;
            }
            __syncthreads();

            const unsigned short (*Ab)[264] = (z == 2) ? Xt : Wt;
            const unsigned short (*Bb)[264] = (z == 2) ? Wt : Xt;

            f32x4 acc[2][2] = {};
#pragma unroll
            for (int kk = 0; kk < 8; ++kk) {
                bf16x8 a[2], bfr[2];
#pragma unroll
                for (int f = 0; f < 2; ++f) {
                    a[f]   = *reinterpret_cast<const bf16x8*>(&Ab[ar0 + 16 * f + lr][32 * kk + 8 * half]);
                    bfr[f] = *reinterpret_cast<const bf16x8*>(&Bb[br0 + 16 * f + lr][32 * kk + 8 * half]);
                }
#pragma unroll
                for (int fa = 0; fa < 2; ++fa)
#pragma unroll
                    for (int fb = 0; fb < 2; ++fb)
                        acc[fa][fb] = MFMA16(a[fa], bfr[fb], acc[fa][fb], 0, 0, 0);
            }

            if (z == 0) {
#pragma unroll
                for (int fa = 0; fa < 2; ++fa)
#pragma unroll
                    for (int fb = 0; fb < 2; ++fb) {
                        int m = m0 + br0 + 16 * fb + lr;
                        int o = o0 + ar0 + 16 * fa + 4 * half;
                        u32x2 pk; pk[0] = pack2(acc[fa][fb][0], acc[fa][fb][1]);
                        pk[1] = pack2(acc[fa][fb][2], acc[fa][fb][3]);
                        *reinterpret_cast<u32x2*>(qb + (size_t)m * NH + o) = pk;
                    }
            } else if (z == 1) {
#pragma unroll
                for (int fa = 0; fa < 2; ++fa)
#pragma unroll
                    for (int fb = 0; fb < 2; ++fb) {
                        int m = m0 + br0 + 16 * fb + lr;          // token e
                        int o = o0 + ar0 + 16 * fa + 4 * half;    // k-feature
                        int bb = m >> 11, el = m & 2047;
                        u32x2 pk; pk[0] = pack2(acc[fa][fb][0], acc[fa][fb][1]);
                        pk[1] = pack2(acc[fa][fb][2], acc[fa][fb][3]);
                        size_t idx = (((size_t)bb * 32 + (o >> 3)) * 2048 + el) * 8 + (o & 7);
                        *reinterpret_cast<u32x2*>(kb + idx) = pk;
                    }
            } else {
#pragma unroll
                for (int fa = 0; fa < 2; ++fa)
#pragma unroll
                    for (int fb = 0; fb < 2; ++fb) {
                        int dg = m0 + ar0 + 16 * fa + 4 * half;   // token e
                        int o  = o0 + br0 + 16 * fb + lr;         // out feature
                        int bb = dg >> 11, el = dg & 2047;
                        u32x2 pk; pk[0] = pack2(acc[fa][fb][0], acc[fa][fb][1]);
                        pk[1] = pack2(acc[fa][fb][2], acc[fa][fb][3]);
                        size_t idx = (((size_t)bb * 256 + (el >> 3)) * 256 + o) * 8 + (el & 7);
                        *reinterpret_cast<u32x2*>(vT + idx) = pk;
                    }
            }
        }
    }
}

// ---------------------------------------------------------------------------
// Kernel 2: flash attention partials — best-measured R5/R6 structure + mask32.
// 32-e tiles, double-buffered conflict-free K/V (64KB LDS), 8 waves.
// SIDES=1: each wave owns 32 q-rows x ALL 256 o (no QK duplication),
// single 16-deep QK chain, acc[8]. Mask: 1 coalesced u32/tile, prefetched.
// In-register P (cvt_pk+permlane32_swap), defer-max, setprio on MFMA.
// ---------------------------------------------------------------------------
template<int ESP, int SIDES>
__global__ __launch_bounds__(512, 2) void attn_kernel(
    const unsigned short* __restrict__ qb, const unsigned short* __restrict__ kb,
    const unsigned short* __restrict__ vT, const unsigned int* __restrict__ mask32,
    unsigned short* __restrict__ part, float* __restrict__ mpart, float* __restrict__ lpart)
{
    constexpr int GROUPS = 8 / SIDES;        // q-groups per block
    constexpr int QB = 32 * GROUPS;          // q-rows per block
    constexpr int NOT = 8 / SIDES;           // 32-o tiles per wave
    constexpr int NT = (ND / ESP) / 32;      // 32-e tiles per block

    __shared__ unsigned char KT[2][16384];   // [koct 32][e 32][16B]
    __shared__ unsigned char VTl[2][16384];  // [eoct 4][o 256][16B]

    const int bid = blockIdx.x;
    const int b = bid & 7, es0 = (bid >> 3) & (ESP - 1), qt = bid / (8 * ESP);
    const int t = threadIdx.x, w = t >> 6, l = t & 63;
    const int lo32 = l & 31, hi = l >> 5;
    const int g = w & (GROUPS - 1), side = w / GROUPS;
    const int qbase = qt * QB + g * 32;
    const int obase = side * (256 / SIDES);
    const int ebase = es0 * (ND / ESP);
    const float SC = 0.0625f, L2E = 1.44269504f;

    bf16x8 qf[16];
    {
        const unsigned short* qr = qb + ((size_t)b * ND + qbase + lo32) * NH + 8 * hi;
#pragma unroll
        for (int kk = 0; kk < 16; ++kk)
            qf[kk] = *reinterpret_cast<const bf16x8*>(qr + kk * 16);
    }

    const char* kbc = (const char*)kb + ((size_t)b << 20);
    const char* vtc = (const char*)vT + ((size_t)b << 20);
    const unsigned int* mrow =
        mask32 + ((size_t)b * 64 + es0 * NT) * 2048 + qbase + lo32;

    auto stageK = [&](int buf, int tt) {
        const int e0s = ebase + tt * 32;
#pragma unroll
        for (int i = 0; i < 2; ++i) {
            int off = i * 8192 + t * 16;
            int koct = off >> 9, e = (off >> 4) & 31;
            gload_lds16(kbc + (size_t)koct * 32768 + (size_t)(e0s + e) * 16, &KT[buf][off]);
        }
    };
    auto stageV = [&](int buf, int tt) {
        const int Eb = (ebase + tt * 32) >> 3;
#pragma unroll
        for (int i = 0; i < 2; ++i) {
            int off = i * 8192 + t * 16;
            int eoct = off >> 12, o = (off >> 4) & 255;
            gload_lds16(vtc + (size_t)(Eb + eoct) * 4096 + (size_t)o * 16, &VTl[buf][off]);
        }
    };

    f32x16 acc[NOT] = {};
    float m_run = -__builtin_inff(), l_run = 0.f;

    stageK(0, 0); stageV(0, 0);
    unsigned int m_cur = mrow[0];
    __syncthreads();

#pragma unroll 1
    for (int tt = 0; tt < NT; ++tt) {
        const int cur = tt & 1;
        if (tt < NT - 1) { stageK(cur ^ 1, tt + 1); stageV(cur ^ 1, tt + 1); }
        const unsigned int m_next = (tt + 1 < NT) ? mrow[(size_t)(tt + 1) * 2048] : 0u;

        // ---- QK^T: single 16-deep chain (register-light) ----
        const char* Kc = (const char*)&KT[cur][0];
        f32x16 s = {};
        __builtin_amdgcn_s_setprio(1);
#pragma unroll
        for (int kk = 0; kk < 16; ++kk) {
            bf16x8 kf = *reinterpret_cast<const bf16x8*>(Kc + kk * 1024 + hi * 512 + lo32 * 16);
            s = MFMA32(kf, qf[kk], s, 0, 0, 0);
        }
        __builtin_amdgcn_s_setprio(0);

        // ---- mask (bit-extract) + online softmax (defer-max) ----
        float p[16];
        float tmax = -__builtin_inff();
        const unsigned int mb = m_cur >> (4 * hi);
#pragma unroll
        for (int gg = 0; gg < 4; ++gg) {
            const unsigned int mg = mb >> (8 * gg);
#pragma unroll
            for (int r = 0; r < 4; ++r) {
                float sv = s[gg * 4 + r] * SC;
                sv = ((mg >> r) & 1u) ? sv : -1e9f;
                p[gg * 4 + r] = sv;
                tmax = fmaxf(tmax, sv);
            }
        }
        tmax = fmaxf(tmax, __shfl_xor(tmax, 32));
        if (!__all(tmax <= m_run + 8.0f)) {
            const float m_new = fmaxf(m_run, tmax);
            const float scale = exp2f((m_run - m_new) * L2E);
#pragma unroll
            for (int ot = 0; ot < NOT; ++ot)
#pragma unroll
                for (int r = 0; r < 16; ++r) acc[ot][r] *= scale;
            l_run *= scale;
            m_run = m_new;
        }
        float psum = 0.f;
#pragma unroll
        for (int r2 = 0; r2 < 16; ++r2) {
            float pe = exp2f((p[r2] - m_run) * L2E);
            p[r2] = pe;
            psum += pe;
        }
        psum += __shfl_xor(psum, 32);
        l_run += psum;

        // ---- P -> B-frags fully in-register ----
        unsigned int c0 = cvtpk(p[0], p[1]),   c1 = cvtpk(p[2], p[3]);
        unsigned int c2 = cvtpk(p[4], p[5]),   c3 = cvtpk(p[6], p[7]);
        plswap(c0, c2); plswap(c1, c3);
        unsigned int c4 = cvtpk(p[8], p[9]),   c5 = cvtpk(p[10], p[11]);
        unsigned int c6 = cvtpk(p[12], p[13]), c7 = cvtpk(p[14], p[15]);
        plswap(c4, c6); plswap(c5, c7);
        const bf16x8 pf0 = mk8(c0, c1, c2, c3);
        const bf16x8 pf1 = mk8(c4, c5, c6, c7);

        // ---- PV: this wave's o-range ----
        const char* Vc = (const char*)&VTl[cur][0];
        __builtin_amdgcn_s_setprio(1);
#pragma unroll
        for (int ot = 0; ot < NOT; ++ot) {
            bf16x8 vf = *reinterpret_cast<const bf16x8*>(
                Vc + hi * 4096 + (size_t)(obase + ot * 32 + lo32) * 16);
            acc[ot] = MFMA32(vf, pf0, acc[ot], 0, 0, 0);
        }
#pragma unroll
        for (int ot = 0; ot < NOT; ++ot) {
            bf16x8 vf = *reinterpret_cast<const bf16x8*>(
                Vc + 8192 + hi * 4096 + (size_t)(obase + ot * 32 + lo32) * 16);
            acc[ot] = MFMA32(vf, pf1, acc[ot], 0, 0, 0);
        }
        __builtin_amdgcn_s_setprio(0);

        __syncthreads();
        m_cur = m_next;
    }

    // ---- epilogue: unnormalized bf16 partials + m/l ----
    const int qg = b * ND + qbase + lo32;
    unsigned short* pb = part + ((size_t)es0 * 16384 + qg) * 256;
#pragma unroll
    for (int ot = 0; ot < NOT; ++ot)
#pragma unroll
        for (int g2 = 0; g2 < 4; ++g2) {
            u32x2 pk;
            pk[0] = pack2(acc[ot][g2 * 4 + 0], acc[ot][g2 * 4 + 1]);
            pk[1] = pack2(acc[ot][g2 * 4 + 2], acc[ot][g2 * 4 + 3]);
            *reinterpret_cast<u32x2*>(pb + obase + ot * 32 + g2 * 8 + 4 * hi) = pk;
        }
    if (hi == 0 && side == 0) {
        mpart[(size_t)es0 * 16384 + qg] = m_run;
        lpart[(size_t)es0 * 16384 + qg] = l_run;
    }
}

// ---------------------------------------------------------------------------
// Kernel 3: fused combine + out-projection + residual + LayerNorm.
// ---------------------------------------------------------------------------
template<int ESP>
__global__ __launch_bounds__(256) void fuse_kernel(
    const unsigned short* __restrict__ part, const float* __restrict__ mpart,
    const float* __restrict__ lpart, const float* __restrict__ Wp,
    const float* __restrict__ bp, const float* __restrict__ x,
    const float* __restrict__ gamma, const float* __restrict__ beta,
    float* __restrict__ out)
{
    __shared__ unsigned short Xt[64][264];
    __shared__ unsigned short Wt[64][264];
    __shared__ float hL[64][264];
    __shared__ float cel[64][ESP];

    const int M0 = blockIdx.x * 64;
    const int t = threadIdx.x;
    const float L2E = 1.44269504f;

    if (t < 64) {
        float me[ESP], le[ESP], M = -__builtin_inff();
#pragma unroll
        for (int e = 0; e < ESP; ++e) {
            me[e] = mpart[(size_t)e * 16384 + M0 + t];
            le[e] = lpart[(size_t)e * 16384 + M0 + t];
            M = fmaxf(M, me[e]);
        }
        float wsum = 0.f;
#pragma unroll
        for (int e = 0; e < ESP; ++e) { me[e] = exp2f((me[e] - M) * L2E); wsum += me[e] * le[e]; }
        const float inv = 1.f / wsum;
#pragma unroll
        for (int e = 0; e < ESP; ++e) cel[t][e] = me[e] * inv;
    }
#pragma unroll
    for (int i = 0; i < 16; ++i) {
        int fidx = i * 256 + t, row = fidx >> 6, c4 = fidx & 63;
        f32x4 vW = *reinterpret_cast<const f32x4*>(Wp + (size_t)row * NH + c4 * 4);
        u32x2 pw; pw[0] = pack2(vW[0], vW[1]); pw[1] = pack2(vW[2], vW[3]);
        *reinterpret_cast<u32x2*>(&Wt[row][c4 * 4]) = pw;
    }
    __syncthreads();

#pragma unroll
    for (int i = 0; i < 8; ++i) {
        int fidx = i * 256 + t, row = fidx >> 5, c8 = fidx & 31;
        float o[8] = {};
#pragma unroll
        for (int e = 0; e < ESP; ++e) {
            u32x4 v = *reinterpret_cast<const u32x4*>(
                part + (((size_t)e * 16384 + M0 + row) * 256 + c8 * 8));
            const float ce = cel[row][e];
#pragma unroll
            for (int j = 0; j < 4; ++j) {
                o[2 * j]     += ce * bflo(v[j]);
                o[2 * j + 1] += ce * bfhi(v[j]);
            }
        }
        u32x4 pk;
#pragma unroll
        for (int j = 0; j < 4; ++j) pk[j] = pack2(o[2 * j], o[2 * j + 1]);
        *reinterpret_cast<u32x4*>(&Xt[row][c8 * 8]) = pk;
    }
    __syncthreads();

    const int w = t >> 6, lane = t & 63, lr = lane & 15, half = lane >> 4;
    const int ar0 = 32 * (w >> 1), br0 = 32 * (w & 1);

    for (int pc = 0; pc < 4; ++pc) {
        f32x4 acc[2][2] = {};
#pragma unroll
        for (int kk = 0; kk < 8; ++kk) {
            bf16x8 a[2], bfr[2];
#pragma unroll
            for (int f = 0; f < 2; ++f) {
                a[f]   = *reinterpret_cast<const bf16x8*>(&Wt[ar0 + 16 * f + lr][32 * kk + 8 * half]);
                bfr[f] = *reinterpret_cast<const bf16x8*>(&Xt[br0 + 16 * f + lr][32 * kk + 8 * half]);
            }
#pragma unroll
            for (int fa = 0; fa < 2; ++fa)
#pragma unroll
                for (int fb = 0; fb < 2; ++fb)
                    acc[fa][fb] = MFMA16(a[fa], bfr[fb], acc[fa][fb], 0, 0, 0);
        }
#pragma unroll
        for (int fa = 0; fa < 2; ++fa)
#pragma unroll
            for (int fb = 0; fb < 2; ++fb) {
                int p = pc * 64 + ar0 + 16 * fa + 4 * half;
                int m = br0 + 16 * fb + lr;
                *reinterpret_cast<f32x4*>(&hL[m][p]) = acc[fa][fb];
            }
        if (pc < 3) {
            __syncthreads();
#pragma unroll
            for (int i = 0; i < 16; ++i) {
                int fidx = i * 256 + t, row = fidx >> 6, c4 = fidx & 63;
                f32x4 vW = *reinterpret_cast<const f32x4*>(
                    Wp + (size_t)((pc + 1) * 64 + row) * NH + c4 * 4);
                u32x2 pw; pw[0] = pack2(vW[0], vW[1]); pw[1] = pack2(vW[2], vW[3]);
                *reinterpret_cast<u32x2*>(&Wt[row][c4 * 4]) = pw;
            }
            __syncthreads();
        }
    }
    __syncthreads();

    f32x4 gm = *reinterpret_cast<const f32x4*>(gamma + lane * 4);
    f32x4 be = *reinterpret_cast<const f32x4*>(beta + lane * 4);
    f32x4 bv = *reinterpret_cast<const f32x4*>(bp + lane * 4);
    for (int rr = 0; rr < 16; ++rr) {
        const int row = w * 16 + rr;
        f32x4 v = *reinterpret_cast<const f32x4*>(&hL[row][lane * 4]);
        f32x4 xr = *reinterpret_cast<const f32x4*>(x + (size_t)(M0 + row) * NH + lane * 4);
#pragma unroll
        for (int r = 0; r < 4; ++r) v[r] += xr[r] + bv[r];
        float s = v[0] + v[1] + v[2] + v[3];
#pragma unroll
        for (int off = 1; off < 64; off <<= 1) s += __shfl_xor(s, off);
        const float mu = s * (1.f / 256.f);
        f32x4 dv; float q = 0.f;
#pragma unroll
        for (int r = 0; r < 4; ++r) { dv[r] = v[r] - mu; q += dv[r] * dv[r]; }
#pragma unroll
        for (int off = 1; off < 64; off <<= 1) q += __shfl_xor(q, off);
        const float rs = rsqrtf(q * (1.f / 256.f) + 1e-5f);
        f32x4 o;
#pragma unroll
        for (int r = 0; r < 4; ++r) o[r] = dv[r] * rs * gm[r] + be[r];
        *reinterpret_cast<f32x4*>(out + (size_t)(M0 + row) * NH + lane * 4) = o;
    }
}

extern "C" void kernel_launch(void* const* d_in, const int* in_sizes, int n_in,
                              void* d_out, int out_size, void* d_ws, size_t ws_size,
                              hipStream_t stream)
{
    const float* x     = (const float*)d_in[0];
    const int*   adj   = (const int*)d_in[1];
    const float* Wq    = (const float*)d_in[2];
    const float* Wk    = (const float*)d_in[3];
    const float* Wv    = (const float*)d_in[4];
    const float* Wp    = (const float*)d_in[5];
    const float* bp    = (const float*)d_in[6];
    const float* gamma = (const float*)d_in[7];
    const float* beta  = (const float*)d_in[8];

    char* ws = (char*)d_ws;
    const size_t MB = 1024 * 1024;
    unsigned short* qb    = (unsigned short*)(ws);
    unsigned short* kb    = (unsigned short*)(ws + 8 * MB);
    unsigned short* vT    = (unsigned short*)(ws + 16 * MB);
    unsigned short* partb = (unsigned short*)(ws + 24 * MB);
    float* out = (float*)d_out;

    const bool big = ws_size >= (size_t)62 * MB;
    if (big) {
        float* mpart = (float*)(ws + 56 * MB);
        float* lpart = (float*)(ws + 56 * MB + 256 * 1024);
        unsigned int* mask32 = (unsigned int*)(ws + 57 * MB);
        prep_kernel<<<dim3(768), 256, 0, stream>>>(x, Wq, Wk, Wv, adj, qb, kb, vT, mask32);
        attn_kernel<4, 1><<<dim3(256), 512, 0, stream>>>(qb, kb, vT, mask32, partb, mpart, lpart);
        fuse_kernel<4><<<dim3(256), 256, 0, stream>>>(partb, mpart, lpart, Wp, bp, x, gamma, beta, out);
    } else {
        float* mpart = (float*)(ws + 40 * MB);
        float* lpart = (float*)(ws + 40 * MB + 128 * 1024);
        unsigned int* mask32 = (unsigned int*)(ws + 41 * MB);
        prep_kernel<<<dim3(768), 256, 0, stream>>>(x, Wq, Wk, Wv, adj, qb, kb, vT, mask32);
        attn_kernel<2, 2><<<dim3(256), 512, 0, stream>>>(qb, kb, vT, mask32, partb, mpart, lpart);
        fuse_kernel<2><<<dim3(256), 256, 0, stream>>>(partb, mpart, lpart, Wp, bp, x, gamma, beta, out);
    }
}